// Round 15
// baseline (510.026 us; speedup 1.0000x reference)
//
#include <hip/hip_runtime.h>

typedef unsigned short u16;
typedef __bf16 bf16x4 __attribute__((ext_vector_type(4)));
typedef __bf16 bf16x8 __attribute__((ext_vector_type(8)));
typedef float f32x4 __attribute__((ext_vector_type(4)));
typedef u16 u16x4 __attribute__((ext_vector_type(4)));
typedef u16 u16x8 __attribute__((ext_vector_type(8)));

#define AS1P(p) ((__attribute__((address_space(1))) void*)(unsigned long long)(p))
#define AS3P(p) ((__attribute__((address_space(3))) void*)(unsigned long long)(p))
#define MFMA16(a, b, c) __builtin_amdgcn_mfma_f32_16x16x32_bf16((a), (b), (c), 0, 0, 0)

__device__ __forceinline__ u16 f2b(float x) { return __builtin_bit_cast(u16, (__bf16)x); }
__device__ __forceinline__ float b2f(u16 u) {
  return __builtin_bit_cast(float, (unsigned)u << 16);
}

// ---------------- elementwise f32 -> bf16 ----------------
__global__ __launch_bounds__(256) void cvt_f32_bf16(const float* __restrict__ in,
                                                    u16* __restrict__ out, int n4) {
  int stride = gridDim.x * blockDim.x;
  for (int i = blockIdx.x * blockDim.x + threadIdx.x; i < n4; i += stride) {
    f32x4 v = *(const f32x4*)(in + (long)i * 4);
    u16x4 o;
    o[0] = f2b(v[0]); o[1] = f2b(v[1]); o[2] = f2b(v[2]); o[3] = f2b(v[3]);
    *(u16x4*)(out + (long)i * 4) = o;
  }
}

// ---------------- weight transpose f32[K][N] -> bf16[N][K] ----------------
__global__ __launch_bounds__(256) void wtrans(const float* __restrict__ W,
                                              u16* __restrict__ Wt, int K, int N) {
  __shared__ float tile[32][33];
  int nbk = K >> 5;
  int bk = blockIdx.x % nbk;
  int bn = blockIdx.x / nbk;
  int tx = threadIdx.x & 31, ty = threadIdx.x >> 5;  // 32 x 8
#pragma unroll
  for (int i = 0; i < 32; i += 8)
    tile[ty + i][tx] = W[(long)(bk * 32 + ty + i) * N + bn * 32 + tx];
  __syncthreads();
#pragma unroll
  for (int i = 0; i < 32; i += 8)
    Wt[(long)(bn * 32 + ty + i) * K + bk * 32 + tx] = f2b(tile[tx][ty + i]);
}

// ---------------- v transpose: kvb v-half [8][256][2048(+1024)] -> [8][1024][256] ------
__global__ __launch_bounds__(256) void vtrans(const u16* __restrict__ kvb,
                                              u16* __restrict__ vt) {
  __shared__ u16 tile[32][33];
  int bt = blockIdx.x & 7;          // Se/32
  int bd = (blockIdx.x >> 3) & 31;  // D/32
  int bc = blockIdx.x >> 8;         // 8
  int tx = threadIdx.x & 31, ty = threadIdx.x >> 5;
  const long ob = (long)bc * 1024 * 256;
  const float RS = 1.0f / 64.0f;  // C/Se
#pragma unroll
  for (int i = 0; i < 32; i += 8)
    tile[ty + i][tx] =
        kvb[((long)bc * 256 + bt * 32 + ty + i) * 2048 + 1024 + bd * 32 + tx];
  __syncthreads();
#pragma unroll
  for (int i = 0; i < 32; i += 8)
    vt[ob + (long)(bd * 32 + ty + i) * 256 + bt * 32 + tx] =
        f2b(b2f(tile[tx][ty + i]) * RS);
}

// ---------------- K fragmentizer: kvb k-half [BC][Se][2048] -> MFMA B-frag order -------
__global__ __launch_bounds__(256) void kfrag_build(const u16* __restrict__ kvb,
                                                   u16* __restrict__ kfrag) {
  int wv = ((int)blockIdx.x << 2) + (threadIdx.x >> 6);  // 0..4095
  int lane = threadIdx.x & 63, lr = lane & 15, lg = lane >> 4;
  int ks = wv & 1, tsl = (wv >> 1) & 1, c = (wv >> 2) & 3;
  int ch = (wv >> 4) & 7, h = (wv >> 7) & 15, b = (wv >> 11) & 1;
  const u16* src = kvb + ((long)(c * 2 + b) * 256 + ch * 32 + tsl * 16 + lr) * 2048 +
                   h * 64 + ks * 32 + lg * 8;
  *(bf16x8*)(kfrag + (long)wv * 512 + lane * 8) = *(const bf16x8*)src;
}

// ---------------- V fragmentizer: vtb[BC][D][Se] -> MFMA B-frag order ------------------
__global__ __launch_bounds__(256) void vfrag_build(const u16* __restrict__ vtb,
                                                   u16* __restrict__ vfrag) {
  int wv = ((int)blockIdx.x << 2) + (threadIdx.x >> 6);  // 0..4095
  int lane = threadIdx.x & 63, lr = lane & 15, lg = lane >> 4;
  int dsu = wv & 3, c = (wv >> 2) & 3;
  int ch = (wv >> 4) & 7, h = (wv >> 7) & 15, b = (wv >> 11) & 1;
  const u16* src = vtb + ((long)(c * 2 + b) * 1024 + h * 64 + dsu * 16 + lr) * 256 +
                   ch * 32 + lg * 8;
  *(bf16x8*)(vfrag + (long)wv * 512 + lane * 8) = *(const bf16x8*)src;
}

// ---------------- GEMM 128^2 (proven): C[M,N] = A[M,K] @ Bt[N,K]^T ---------------------
__global__ __launch_bounds__(256) void gemm_bt(
    const u16* __restrict__ A, const u16* __restrict__ Bt,
    u16* __restrict__ outb, int M, int N, int K, float ascale) {
  __shared__ u16 lA[128 * 64];
  __shared__ u16 lB[128 * 64];
  const int tid = threadIdx.x;
  const int lane = tid & 63;
  const int wid = tid >> 6;
  const int wm = wid >> 1, wn = wid & 1;
  const int lr = lane & 15, lg = lane >> 4;

  int bid = (int)blockIdx.x;
  int nwg = (int)gridDim.x;
  if ((nwg & 7) == 0) bid = (bid & 7) * (nwg >> 3) + (bid >> 3);

  const int nbn = N >> 7;
  const int bm = bid / nbn;
  const int bn = bid % nbn;
  const long arow0 = (long)bm * 128;
  const long brow0 = (long)bn * 128;

  f32x4 acc[4][4] = {};

  const int srow = tid >> 3;
  const int scol = tid & 7;

  for (int k0 = 0; k0 < K; k0 += 64) {
#pragma unroll
    for (int i = 0; i < 4; ++i) {
      int row = i * 32 + srow;
      int kc = scol ^ (row & 7);
      __builtin_amdgcn_global_load_lds(AS1P(A + (arow0 + row) * K + k0 + kc * 8),
                                       AS3P(lA + i * 2048 + (tid & ~63) * 8), 16, 0, 0);
    }
#pragma unroll
    for (int i = 0; i < 4; ++i) {
      int row = i * 32 + srow;
      int kc = scol ^ (row & 7);
      __builtin_amdgcn_global_load_lds(AS1P(Bt + (brow0 + row) * K + k0 + kc * 8),
                                       AS3P(lB + i * 2048 + (tid & ~63) * 8), 16, 0, 0);
    }
    asm volatile("s_waitcnt vmcnt(0)" ::: "memory");
    __syncthreads();

#pragma unroll
    for (int ks = 0; ks < 2; ++ks) {
      bf16x8 af[4], bfr[4];
#pragma unroll
      for (int m = 0; m < 4; ++m) {
        int row = wm * 64 + m * 16 + lr;
        int off = row * 128 + ks * 64 + lg * 16;
        off ^= (row & 7) << 4;
        af[m] = *(const bf16x8*)((const char*)lA + off);
      }
#pragma unroll
      for (int n = 0; n < 4; ++n) {
        int row = wn * 64 + n * 16 + lr;
        int off = row * 128 + ks * 64 + lg * 16;
        off ^= (row & 7) << 4;
        bfr[n] = *(const bf16x8*)((const char*)lB + off);
      }
#pragma unroll
      for (int m = 0; m < 4; ++m)
#pragma unroll
        for (int n = 0; n < 4; ++n)
          acc[m][n] = MFMA16(af[m], bfr[n], acc[m][n]);
    }
    __syncthreads();
  }

#pragma unroll
  for (int m = 0; m < 4; ++m)
#pragma unroll
    for (int n = 0; n < 4; ++n) {
      long col = brow0 + wn * 64 + n * 16 + lr;
#pragma unroll
      for (int r = 0; r < 4; ++r) {
        long row = arow0 + wm * 64 + m * 16 + lg * 4 + r;
        outb[row * N + col] = f2b(acc[m][n][r] * ascale);
      }
    }
}

// ---------------- GEMM 256^2 stage-ahead 2-phase (R12 proven) --------------------------
// MODE 0: write bf16 C*ascale.
// MODE 1: write f32 C + bias[n] + b2f(residb[m*N+n]) (nontemporal f32 out).
template <int MODE>
__global__ __launch_bounds__(512, 2) void gemm256(
    const u16* __restrict__ A, const u16* __restrict__ Bt,
    u16* __restrict__ outb, float* __restrict__ outf,
    const float* __restrict__ bias, const u16* __restrict__ residb,
    int M, int N, int K, float ascale) {
  __shared__ u16 lds[2][2][256 * 64];  // [buf][A=0/B=1][row*64 + slot*8 + e]
  const int tid = threadIdx.x;
  const int lane = tid & 63;
  const int wid = tid >> 6;      // 0..7
  const int wm = wid >> 2;       // 0..1
  const int wn = wid & 3;        // 0..3
  const int lr = lane & 15, lg = lane >> 4;

  int bid = (int)blockIdx.x;
  int nwg = (int)gridDim.x;
  bid = (bid & 7) * (nwg >> 3) + (bid >> 3);  // nwg % 8 == 0 for all our launches

  const int nbn = N >> 8;
  const int bm = bid / nbn;
  const int bn = bid % nbn;
  const long arow0 = (long)bm * 256;
  const long brow0 = (long)bn * 256;

  f32x4 acc[8][4] = {};

  const int srow = tid >> 3;  // 0..63
  const int scol = tid & 7;
  const int nt = K >> 6;

#define STAGE256(bf, t)                                                                \
  do {                                                                                 \
    int k0_ = (t) << 6;                                                                \
    _Pragma("unroll") for (int i = 0; i < 4; ++i) {                                    \
      int row = i * 64 + srow;                                                         \
      int kc = scol ^ (row & 7);                                                       \
      __builtin_amdgcn_global_load_lds(AS1P(A + (arow0 + row) * K + k0_ + kc * 8),     \
                                       AS3P(&lds[bf][0][0] + i * 4096 + (tid & ~63) * 8), \
                                       16, 0, 0);                                      \
    }                                                                                  \
    _Pragma("unroll") for (int i = 0; i < 4; ++i) {                                    \
      int row = i * 64 + srow;                                                         \
      int kc = scol ^ (row & 7);                                                       \
      __builtin_amdgcn_global_load_lds(AS1P(Bt + (brow0 + row) * K + k0_ + kc * 8),    \
                                       AS3P(&lds[bf][1][0] + i * 4096 + (tid & ~63) * 8), \
                                       16, 0, 0);                                      \
    }                                                                                  \
  } while (0)

#define COMPUTE256(bf)                                                                 \
  do {                                                                                 \
    _Pragma("unroll") for (int ks = 0; ks < 2; ++ks) {                                 \
      bf16x8 af[8], bfr[4];                                                            \
      _Pragma("unroll") for (int m = 0; m < 8; ++m) {                                  \
        int row = wm * 128 + m * 16 + lr;                                              \
        int off = row * 128 + ks * 64 + lg * 16;                                       \
        off ^= (row & 7) << 4;                                                         \
        af[m] = *(const bf16x8*)((const char*)&lds[bf][0][0] + off);                   \
      }                                                                                \
      _Pragma("unroll") for (int n = 0; n < 4; ++n) {                                  \
        int row = wn * 64 + n * 16 + lr;                                               \
        int off = row * 128 + ks * 64 + lg * 16;                                       \
        off ^= (row & 7) << 4;                                                         \
        bfr[n] = *(const bf16x8*)((const char*)&lds[bf][1][0] + off);                  \
      }                                                                                \
      _Pragma("unroll") for (int m = 0; m < 8; ++m)                                    \
          _Pragma("unroll") for (int n = 0; n < 4; ++n)                                \
              acc[m][n] = MFMA16(af[m], bfr[n], acc[m][n]);                            \
    }                                                                                  \
  } while (0)

  STAGE256(0, 0);
  asm volatile("s_waitcnt vmcnt(0)" ::: "memory");
  __syncthreads();
  int cur = 0;
  for (int t = 0; t < nt - 1; ++t) {
    STAGE256(cur ^ 1, t + 1);  // issue next-tile loads first: latency hides under compute
    COMPUTE256(cur);
    asm volatile("s_waitcnt vmcnt(0)" ::: "memory");
    __syncthreads();
    cur ^= 1;
  }
  COMPUTE256(cur);

  // epilogue: C/D layout row=(lane>>4)*4+r, col=lane&15
#pragma unroll
  for (int m = 0; m < 8; ++m)
#pragma unroll
    for (int n = 0; n < 4; ++n) {
      long col = brow0 + wn * 64 + n * 16 + lr;
#pragma unroll
      for (int r = 0; r < 4; ++r) {
        long row = arow0 + wm * 128 + m * 16 + lg * 4 + r;
        float v = acc[m][n][r];
        if (MODE == 1) {
          long idx = row * N + col;
          __builtin_nontemporal_store(v + bias[col] + b2f(residb[idx]), outf + idx);
        } else {
          outb[row * N + col] = f2b(v * ascale);
        }
      }
    }
#undef STAGE256
#undef COMPUTE256
}

// ---------------- fused decomposing attention (v9b: 8 waves, FIXED launch bounds) -----
// grid: 512 blocks (b2 x h16 x sblk16), block 512 = 8 waves x 32 s-rows each.
// v9's regression was __launch_bounds__(512,2): min-waves=2 caps VGPR at 128 -> the
// ~220-reg live set spilled (WRITE 583MB). Fix: min-waves=1 -> up to 512 VGPR budget;
// occupancy 2 waves/SIMD comes naturally from LDS (139KB -> 1 block/CU = 8 waves/CU),
// achieved as long as allocator lands <= 256 VGPR (live-set estimate ~220-240).
// Same proven per-wave structure as v8: shared kvs staging + wave-private P slab.
__global__ __launch_bounds__(512, 1) void attn_fused(
    const u16* q,                   // [BC][S][D] bf16 (scaled); also output (attn)
    const u16* __restrict__ kfrag,  // [b][h][ch8][16 frags][512]
    const u16* __restrict__ vfrag,  // [b][h][ch8][16 frags][512] (scaled)
    u16* attnout,                   // == q buffer
    float* __restrict__ ent) {      // [B][H][S][Se] f32
  const int B = 2, H = 16, S = 4096, Se = 256, D = 1024;
  __shared__ u16 kvs[2][32 * 512];  // [buf][frag 0..15=K,16..31=V][lane*8] : 32KB/buf
  __shared__ u16 ldsP[8 * 4608];    // per wave: [c:4][s:32][pitch 36] = 9216B
  const int tid = threadIdx.x;
  const int lane = tid & 63, wid = tid >> 6;  // 8 waves
  const int lr = lane & 15, lg = lane >> 4;
  int bid = (int)blockIdx.x;
  bid = (bid & 7) * 64 + (bid >> 3);  // XCD swizzle (512 blocks)
  const int sblk = bid & 15;
  const int h = (bid >> 4) & 15;
  const int b = bid >> 8;
  const int s0 = sblk * 256 + wid * 32;

  u16* Pw = ldsP + wid * 4608;

  // Q fragments: [c][st][ks], A-frag row=st*16+lr
  bf16x8 qf[4][2][2];
#pragma unroll
  for (int c = 0; c < 4; ++c)
#pragma unroll
    for (int st = 0; st < 2; ++st)
#pragma unroll
      for (int ks = 0; ks < 2; ++ks)
        qf[c][st][ks] =
            *(const bf16x8*)(q + ((c * B + b) * (long)S + s0 + st * 16 + lr) * D +
                             h * 64 + ks * 32 + lg * 8);

  const u16* kbh = kfrag + (long)(b * 16 + h) * 65536;
  const u16* vbh = vfrag + (long)(b * 16 + h) * 65536;
  float* entp = ent + ((long)(b * H + h) * S + s0 + lg * 4) * Se + lr;

  const float LN2 = 0.69314718056f;
  const int g0 = wid * 4;  // this wave stages fragments g0..g0+3

  f32x4 oacc[4][4][2] = {};  // [c][dsu][st]

#define STAGEKV(buf, ch)                                                               \
  do {                                                                                 \
    _Pragma("unroll") for (int j = 0; j < 4; ++j) {                                    \
      int f = g0 + j;                                                                  \
      const u16* src = (f < 16 ? kbh + (ch) * 8192 + f * 512                           \
                               : vbh + (ch) * 8192 + (f - 16) * 512) +                 \
                       lane * 8;                                                       \
      __builtin_amdgcn_global_load_lds(AS1P(src), AS3P(&kvs[buf][f * 512]), 16, 0, 0); \
    }                                                                                  \
  } while (0)

  // prologue: stage chunk 0
  STAGEKV(0, 0);
  __syncthreads();

#pragma unroll
  for (int ch = 0; ch < 8; ++ch) {
    const int cur = ch & 1;
    if (ch < 7) STAGEKV(cur ^ 1, ch + 1);  // stage-ahead: drained at chunk-end barrier
    const u16* KV = kvs[cur];

    // ---- QK^T: kf read once from shared LDS, used for both st subtiles
    f32x4 sacc[2][4][2] = {};  // [st][c][tsl]
#pragma unroll
    for (int c = 0; c < 4; ++c)
#pragma unroll
      for (int tsl = 0; tsl < 2; ++tsl)
#pragma unroll
        for (int ks = 0; ks < 2; ++ks) {
          bf16x8 kfv = *(const bf16x8*)(KV + (c * 4 + tsl * 2 + ks) * 512 + lane * 8);
#pragma unroll
          for (int st = 0; st < 2; ++st)
            sacc[st][c][tsl] = MFMA16(qf[c][st][ks], kfv, sacc[st][c][tsl]);
        }

    // ---- in-lane component softmax + entropy + P write
#pragma unroll
    for (int st = 0; st < 2; ++st) {
#pragma unroll
      for (int tsl = 0; tsl < 2; ++tsl) {
#pragma unroll
        for (int r = 0; r < 4; ++r) {
          float t0 = sacc[st][0][tsl][r];
          float t1 = sacc[st][1][tsl][r];
          float t2 = sacc[st][2][tsl][r];
          float t3 = sacc[st][3][tsl][r];
          float e0 = __builtin_amdgcn_exp2f(t0);
          float e1 = __builtin_amdgcn_exp2f(t1);
          float e2 = __builtin_amdgcn_exp2f(t2);
          float e3 = __builtin_amdgcn_exp2f(t3);
          float sum = (e0 + e1) + (e2 + e3);
          float inv = __builtin_amdgcn_rcpf(sum);
          float l2s = __builtin_amdgcn_logf(sum);
          float w0 = e0 * inv, w1 = e1 * inv, w2 = e2 * inv, w3 = e3 * inv;
          float entv = (w0 * t0 + w1 * t1 + w2 * t2 + w3 * t3 - l2s) * LN2;
          __builtin_nontemporal_store(
              entv, entp + (st * 16 + r) * Se + ch * 32 + tsl * 16);
          int prow = st * 16 + lg * 4 + r;
          int pof = prow * 36 + tsl * 16 + lr;
          Pw[0 * 1152 + pof] = f2b(w0);
          Pw[1 * 1152 + pof] = f2b(w1);
          Pw[2 * 1152 + pof] = f2b(w2);
          Pw[3 * 1152 + pof] = f2b(w3);
        }
      }
    }

    // ---- PV: vf read once per (c,dsu), used for both st; pf per (c,st)
#pragma unroll
    for (int c = 0; c < 4; ++c) {
      bf16x8 pf[2];
#pragma unroll
      for (int st = 0; st < 2; ++st) {
        union { bf16x4 hh[2]; bf16x8 v; } pu;
        pu.hh[0] = *(const bf16x4*)(Pw + c * 1152 + (st * 16 + lr) * 36 + lg * 8);
        pu.hh[1] = *(const bf16x4*)(Pw + c * 1152 + (st * 16 + lr) * 36 + lg * 8 + 4);
        pf[st] = pu.v;
      }
#pragma unroll
      for (int dsu = 0; dsu < 4; ++dsu) {
        bf16x8 vfv = *(const bf16x8*)(KV + (16 + c * 4 + dsu) * 512 + lane * 8);
        oacc[c][dsu][0] = MFMA16(pf[0], vfv, oacc[c][dsu][0]);
        oacc[c][dsu][1] = MFMA16(pf[1], vfv, oacc[c][dsu][1]);
      }
    }

    __syncthreads();  // drains stage(ch+1) loads + syncs waves before buffer swap
  }

  // ---- epilogue: write attn out bf16 (into the q buffer region this block read)
#pragma unroll
  for (int c = 0; c < 4; ++c)
#pragma unroll
    for (int dsu = 0; dsu < 4; ++dsu)
#pragma unroll
      for (int st = 0; st < 2; ++st)
#pragma unroll
        for (int r = 0; r < 4; ++r) {
          long s = s0 + st * 16 + lg * 4 + r;
          attnout[((c * B + b) * (long)S + s) * D + h * 64 + dsu * 16 + lr] =
              f2b(oacc[c][dsu][st][r]);
        }
#undef STAGEKV
}

extern "C" void kernel_launch(void* const* d_in, const int* in_sizes, int n_in,
                              void* d_out, int out_size, void* d_ws, size_t ws_size,
                              hipStream_t stream) {
  const float* hs  = (const float*)d_in[0];  // [8,4096,1024]
  const float* ehs = (const float*)d_in[1];  // [8,256,2048]
  const float* Wq  = (const float*)d_in[2];  // [1024,1024]
  const float* Wk  = (const float*)d_in[3];  // [2048,1024]
  const float* Wv  = (const float*)d_in[4];  // [2048,1024]
  const float* Wo  = (const float*)d_in[5];  // [1024,1024]
  const float* bo  = (const float*)d_in[6];  // [1024]
  float* out = (float*)d_out;
  float* ent = out + (size_t)8 * 4096 * 1024;

  char* ws = (char*)d_ws;
  u16* hsb   = (u16*)(ws);              // 67,108,864 B bf16 hs (kept for residual)
  u16* ehsb  = (u16*)(ws + 67108864);   //  8,388,608 B (dead after KV GEMM)
  u16* kfrag = (u16*)(ws + 67108864);   //  4,194,304 B (overwrites ehsb after last use)
  u16* vfrag = (u16*)(ws + 71303168);   //  4,194,304 B
  u16* wqT   = (u16*)(ws + 75497472);   //  2,097,152 B
  u16* wkT   = (u16*)(ws + 77594624);   //  4,194,304 B  \ adjacent: acts as single
  u16* wvT   = (u16*)(ws + 81788928);   //  4,194,304 B  / Bt[2048][2048] for KV GEMM
  u16* woT   = (u16*)(ws + 85983232);   //  2,097,152 B
  u16* qb    = (u16*)(ws + 88080384);   // 67,108,864 B q; attn writes output in-place
  u16* kvb   = (u16*)(ws + 155189248);  //  8,388,608 B  [2048][2048]: k | v
  u16* vtb   = (u16*)(ws + 163577856);  //  4,194,304 B  (end: 167,772,160)

  const float QSCALE = 0.125f * 1.44269504f;  // attn.scale * log2(e)

  cvt_f32_bf16<<<2048, 256, 0, stream>>>(hs, hsb, (8 * 4096 * 1024) / 4);
  cvt_f32_bf16<<<512, 256, 0, stream>>>(ehs, ehsb, (8 * 256 * 2048) / 4);
  wtrans<<<1024, 256, 0, stream>>>(Wq, wqT, 1024, 1024);
  wtrans<<<2048, 256, 0, stream>>>(Wk, wkT, 2048, 1024);
  wtrans<<<2048, 256, 0, stream>>>(Wv, wvT, 2048, 1024);
  wtrans<<<1024, 256, 0, stream>>>(Wo, woT, 1024, 1024);
  // q = (hs @ Wq) * scale*log2e  -- 256^2 2-phase GEMM (proven)
  gemm256<0><<<(32768 / 256) * (1024 / 256), 512, 0, stream>>>(
      hsb, wqT, qb, nullptr, nullptr, nullptr, 32768, 1024, 1024, QSCALE);
  // [k|v] = ehs @ [Wk|Wv]  -- fused, 128^2 GEMM, 256 blocks (full GPU)
  gemm_bt<<<(2048 / 128) * (2048 / 128), 256, 0, stream>>>(
      ehsb, wkT, kvb, 2048, 2048, 2048, 1.0f);
  vtrans<<<2048, 256, 0, stream>>>(kvb, vtb);          // v-half, scaled by C/Se
  kfrag_build<<<1024, 256, 0, stream>>>(kvb, kfrag);   // k-half (ehsb now dead)
  vfrag_build<<<1024, 256, 0, stream>>>(vtb, vfrag);
  // fused component-softmax attention; output lands back in qb, entropy -> d_out
  attn_fused<<<512, 512, 0, stream>>>(qb, kfrag, vfrag, qb, ent);
  // out = attn @ Wo + bo + hs(bf16 resid)  -- 256^2 2-phase GEMM
  gemm256<1><<<(32768 / 256) * (1024 / 256), 512, 0, stream>>>(
      qb, woT, nullptr, out, bo, hsb, 32768, 1024, 1024, 1.0f);
}

// Round 16
// 378.876 us; speedup vs baseline: 1.3462x; 1.3462x over previous
//
#include <hip/hip_runtime.h>

typedef unsigned short u16;
typedef __bf16 bf16x4 __attribute__((ext_vector_type(4)));
typedef __bf16 bf16x8 __attribute__((ext_vector_type(8)));
typedef float f32x4 __attribute__((ext_vector_type(4)));
typedef u16 u16x4 __attribute__((ext_vector_type(4)));
typedef u16 u16x8 __attribute__((ext_vector_type(8)));

#define AS1P(p) ((__attribute__((address_space(1))) void*)(unsigned long long)(p))
#define AS3P(p) ((__attribute__((address_space(3))) void*)(unsigned long long)(p))
#define MFMA16(a, b, c) __builtin_amdgcn_mfma_f32_16x16x32_bf16((a), (b), (c), 0, 0, 0)

__device__ __forceinline__ u16 f2b(float x) { return __builtin_bit_cast(u16, (__bf16)x); }
__device__ __forceinline__ float b2f(u16 u) {
  return __builtin_bit_cast(float, (unsigned)u << 16);
}

// ---------------- elementwise f32 -> bf16 ----------------
__global__ __launch_bounds__(256) void cvt_f32_bf16(const float* __restrict__ in,
                                                    u16* __restrict__ out, int n4) {
  int stride = gridDim.x * blockDim.x;
  for (int i = blockIdx.x * blockDim.x + threadIdx.x; i < n4; i += stride) {
    f32x4 v = *(const f32x4*)(in + (long)i * 4);
    u16x4 o;
    o[0] = f2b(v[0]); o[1] = f2b(v[1]); o[2] = f2b(v[2]); o[3] = f2b(v[3]);
    *(u16x4*)(out + (long)i * 4) = o;
  }
}

// ---------------- weight transpose f32[K][N] -> bf16[N][K] ----------------
__global__ __launch_bounds__(256) void wtrans(const float* __restrict__ W,
                                              u16* __restrict__ Wt, int K, int N) {
  __shared__ float tile[32][33];
  int nbk = K >> 5;
  int bk = blockIdx.x % nbk;
  int bn = blockIdx.x / nbk;
  int tx = threadIdx.x & 31, ty = threadIdx.x >> 5;  // 32 x 8
#pragma unroll
  for (int i = 0; i < 32; i += 8)
    tile[ty + i][tx] = W[(long)(bk * 32 + ty + i) * N + bn * 32 + tx];
  __syncthreads();
#pragma unroll
  for (int i = 0; i < 32; i += 8)
    Wt[(long)(bn * 32 + ty + i) * K + bk * 32 + tx] = f2b(tile[tx][ty + i]);
}

// ---------------- v transpose: kvb v-half [8][256][2048(+1024)] -> [8][1024][256] ------
__global__ __launch_bounds__(256) void vtrans(const u16* __restrict__ kvb,
                                              u16* __restrict__ vt) {
  __shared__ u16 tile[32][33];
  int bt = blockIdx.x & 7;          // Se/32
  int bd = (blockIdx.x >> 3) & 31;  // D/32
  int bc = blockIdx.x >> 8;         // 8
  int tx = threadIdx.x & 31, ty = threadIdx.x >> 5;
  const long ob = (long)bc * 1024 * 256;
  const float RS = 1.0f / 64.0f;  // C/Se
#pragma unroll
  for (int i = 0; i < 32; i += 8)
    tile[ty + i][tx] =
        kvb[((long)bc * 256 + bt * 32 + ty + i) * 2048 + 1024 + bd * 32 + tx];
  __syncthreads();
#pragma unroll
  for (int i = 0; i < 32; i += 8)
    vt[ob + (long)(bd * 32 + ty + i) * 256 + bt * 32 + tx] =
        f2b(b2f(tile[tx][ty + i]) * RS);
}

// ---------------- K fragmentizer: kvb k-half [BC][Se][2048] -> MFMA B-frag order -------
__global__ __launch_bounds__(256) void kfrag_build(const u16* __restrict__ kvb,
                                                   u16* __restrict__ kfrag) {
  int wv = ((int)blockIdx.x << 2) + (threadIdx.x >> 6);  // 0..4095
  int lane = threadIdx.x & 63, lr = lane & 15, lg = lane >> 4;
  int ks = wv & 1, tsl = (wv >> 1) & 1, c = (wv >> 2) & 3;
  int ch = (wv >> 4) & 7, h = (wv >> 7) & 15, b = (wv >> 11) & 1;
  const u16* src = kvb + ((long)(c * 2 + b) * 256 + ch * 32 + tsl * 16 + lr) * 2048 +
                   h * 64 + ks * 32 + lg * 8;
  *(bf16x8*)(kfrag + (long)wv * 512 + lane * 8) = *(const bf16x8*)src;
}

// ---------------- V fragmentizer: vtb[BC][D][Se] -> MFMA B-frag order ------------------
__global__ __launch_bounds__(256) void vfrag_build(const u16* __restrict__ vtb,
                                                   u16* __restrict__ vfrag) {
  int wv = ((int)blockIdx.x << 2) + (threadIdx.x >> 6);  // 0..4095
  int lane = threadIdx.x & 63, lr = lane & 15, lg = lane >> 4;
  int dsu = wv & 3, c = (wv >> 2) & 3;
  int ch = (wv >> 4) & 7, h = (wv >> 7) & 15, b = (wv >> 11) & 1;
  const u16* src = vtb + ((long)(c * 2 + b) * 1024 + h * 64 + dsu * 16 + lr) * 256 +
                   ch * 32 + lg * 8;
  *(bf16x8*)(vfrag + (long)wv * 512 + lane * 8) = *(const bf16x8*)src;
}

// ---------------- GEMM 128^2 (proven): C[M,N] = A[M,K] @ Bt[N,K]^T ---------------------
__global__ __launch_bounds__(256) void gemm_bt(
    const u16* __restrict__ A, const u16* __restrict__ Bt,
    u16* __restrict__ outb, int M, int N, int K, float ascale) {
  __shared__ u16 lA[128 * 64];
  __shared__ u16 lB[128 * 64];
  const int tid = threadIdx.x;
  const int lane = tid & 63;
  const int wid = tid >> 6;
  const int wm = wid >> 1, wn = wid & 1;
  const int lr = lane & 15, lg = lane >> 4;

  int bid = (int)blockIdx.x;
  int nwg = (int)gridDim.x;
  if ((nwg & 7) == 0) bid = (bid & 7) * (nwg >> 3) + (bid >> 3);

  const int nbn = N >> 7;
  const int bm = bid / nbn;
  const int bn = bid % nbn;
  const long arow0 = (long)bm * 128;
  const long brow0 = (long)bn * 128;

  f32x4 acc[4][4] = {};

  const int srow = tid >> 3;
  const int scol = tid & 7;

  for (int k0 = 0; k0 < K; k0 += 64) {
#pragma unroll
    for (int i = 0; i < 4; ++i) {
      int row = i * 32 + srow;
      int kc = scol ^ (row & 7);
      __builtin_amdgcn_global_load_lds(AS1P(A + (arow0 + row) * K + k0 + kc * 8),
                                       AS3P(lA + i * 2048 + (tid & ~63) * 8), 16, 0, 0);
    }
#pragma unroll
    for (int i = 0; i < 4; ++i) {
      int row = i * 32 + srow;
      int kc = scol ^ (row & 7);
      __builtin_amdgcn_global_load_lds(AS1P(Bt + (brow0 + row) * K + k0 + kc * 8),
                                       AS3P(lB + i * 2048 + (tid & ~63) * 8), 16, 0, 0);
    }
    asm volatile("s_waitcnt vmcnt(0)" ::: "memory");
    __syncthreads();

#pragma unroll
    for (int ks = 0; ks < 2; ++ks) {
      bf16x8 af[4], bfr[4];
#pragma unroll
      for (int m = 0; m < 4; ++m) {
        int row = wm * 64 + m * 16 + lr;
        int off = row * 128 + ks * 64 + lg * 16;
        off ^= (row & 7) << 4;
        af[m] = *(const bf16x8*)((const char*)lA + off);
      }
#pragma unroll
      for (int n = 0; n < 4; ++n) {
        int row = wn * 64 + n * 16 + lr;
        int off = row * 128 + ks * 64 + lg * 16;
        off ^= (row & 7) << 4;
        bfr[n] = *(const bf16x8*)((const char*)lB + off);
      }
#pragma unroll
      for (int m = 0; m < 4; ++m)
#pragma unroll
        for (int n = 0; n < 4; ++n)
          acc[m][n] = MFMA16(af[m], bfr[n], acc[m][n]);
    }
    __syncthreads();
  }

#pragma unroll
  for (int m = 0; m < 4; ++m)
#pragma unroll
    for (int n = 0; n < 4; ++n) {
      long col = brow0 + wn * 64 + n * 16 + lr;
#pragma unroll
      for (int r = 0; r < 4; ++r) {
        long row = arow0 + wm * 64 + m * 16 + lg * 4 + r;
        outb[row * N + col] = f2b(acc[m][n][r] * ascale);
      }
    }
}

// ---------------- GEMM 256^2 stage-ahead 2-phase (R12 proven) --------------------------
// MODE 0: write bf16 C*ascale.
// MODE 1: write f32 C + bias[n] + b2f(residb[m*N+n]) (nontemporal f32 out).
template <int MODE>
__global__ __launch_bounds__(512, 2) void gemm256(
    const u16* __restrict__ A, const u16* __restrict__ Bt,
    u16* __restrict__ outb, float* __restrict__ outf,
    const float* __restrict__ bias, const u16* __restrict__ residb,
    int M, int N, int K, float ascale) {
  __shared__ u16 lds[2][2][256 * 64];  // [buf][A=0/B=1][row*64 + slot*8 + e]
  const int tid = threadIdx.x;
  const int lane = tid & 63;
  const int wid = tid >> 6;      // 0..7
  const int wm = wid >> 2;       // 0..1
  const int wn = wid & 3;        // 0..3
  const int lr = lane & 15, lg = lane >> 4;

  int bid = (int)blockIdx.x;
  int nwg = (int)gridDim.x;
  bid = (bid & 7) * (nwg >> 3) + (bid >> 3);  // nwg % 8 == 0 for all our launches

  const int nbn = N >> 8;
  const int bm = bid / nbn;
  const int bn = bid % nbn;
  const long arow0 = (long)bm * 256;
  const long brow0 = (long)bn * 256;

  f32x4 acc[8][4] = {};

  const int srow = tid >> 3;  // 0..63
  const int scol = tid & 7;
  const int nt = K >> 6;

#define STAGE256(bf, t)                                                                \
  do {                                                                                 \
    int k0_ = (t) << 6;                                                                \
    _Pragma("unroll") for (int i = 0; i < 4; ++i) {                                    \
      int row = i * 64 + srow;                                                         \
      int kc = scol ^ (row & 7);                                                       \
      __builtin_amdgcn_global_load_lds(AS1P(A + (arow0 + row) * K + k0_ + kc * 8),     \
                                       AS3P(&lds[bf][0][0] + i * 4096 + (tid & ~63) * 8), \
                                       16, 0, 0);                                      \
    }                                                                                  \
    _Pragma("unroll") for (int i = 0; i < 4; ++i) {                                    \
      int row = i * 64 + srow;                                                         \
      int kc = scol ^ (row & 7);                                                       \
      __builtin_amdgcn_global_load_lds(AS1P(Bt + (brow0 + row) * K + k0_ + kc * 8),    \
                                       AS3P(&lds[bf][1][0] + i * 4096 + (tid & ~63) * 8), \
                                       16, 0, 0);                                      \
    }                                                                                  \
  } while (0)

#define COMPUTE256(bf)                                                                 \
  do {                                                                                 \
    _Pragma("unroll") for (int ks = 0; ks < 2; ++ks) {                                 \
      bf16x8 af[8], bfr[4];                                                            \
      _Pragma("unroll") for (int m = 0; m < 8; ++m) {                                  \
        int row = wm * 128 + m * 16 + lr;                                              \
        int off = row * 128 + ks * 64 + lg * 16;                                       \
        off ^= (row & 7) << 4;                                                         \
        af[m] = *(const bf16x8*)((const char*)&lds[bf][0][0] + off);                   \
      }                                                                                \
      _Pragma("unroll") for (int n = 0; n < 4; ++n) {                                  \
        int row = wn * 64 + n * 16 + lr;                                               \
        int off = row * 128 + ks * 64 + lg * 16;                                       \
        off ^= (row & 7) << 4;                                                         \
        bfr[n] = *(const bf16x8*)((const char*)&lds[bf][1][0] + off);                  \
      }                                                                                \
      _Pragma("unroll") for (int m = 0; m < 8; ++m)                                    \
          _Pragma("unroll") for (int n = 0; n < 4; ++n)                                \
              acc[m][n] = MFMA16(af[m], bfr[n], acc[m][n]);                            \
    }                                                                                  \
  } while (0)

  STAGE256(0, 0);
  asm volatile("s_waitcnt vmcnt(0)" ::: "memory");
  __syncthreads();
  int cur = 0;
  for (int t = 0; t < nt - 1; ++t) {
    STAGE256(cur ^ 1, t + 1);  // issue next-tile loads first: latency hides under compute
    COMPUTE256(cur);
    asm volatile("s_waitcnt vmcnt(0)" ::: "memory");
    __syncthreads();
    cur ^= 1;
  }
  COMPUTE256(cur);

  // epilogue: C/D layout row=(lane>>4)*4+r, col=lane&15
#pragma unroll
  for (int m = 0; m < 8; ++m)
#pragma unroll
    for (int n = 0; n < 4; ++n) {
      long col = brow0 + wn * 64 + n * 16 + lr;
#pragma unroll
      for (int r = 0; r < 4; ++r) {
        long row = arow0 + wm * 128 + m * 16 + lg * 4 + r;
        float v = acc[m][n][r];
        if (MODE == 1) {
          long idx = row * N + col;
          __builtin_nontemporal_store(v + bias[col] + b2f(residb[idx]), outf + idx);
        } else {
          outb[row * N + col] = f2b(v * ascale);
        }
      }
    }
#undef STAGE256
#undef COMPUTE256
}

// ---------------- fused decomposing attention (v10: v8 geometry + 2 blocks/CU) --------
// grid: 1024 blocks (b2 x h16 x sblk32), block 256 = 4 waves x 32 s-rows (v8 proven:
// no spill at this width). Change vs v8: kvs SINGLE-buffered (32KB) -> LDS 69.6KB/block
// -> 2 blocks/CU -> 2 waves/SIMD. The per-chunk stage drain is now exposed within a
// block (stage -> __syncthreads with no covering compute) but is hidden by the OTHER
// resident block's compute (m114 wave-level overlap) -- which v8's 1-block/CU lacked.
// v9/v9b lesson: 8-wave blocks force 2-wave/SIMD co-residency -> 128-VGPR cap -> spill;
// 2 blocks/CU with 4-wave blocks reaches the same TLP without the register cap.
__global__ __launch_bounds__(256, 1) void attn_fused(
    const u16* q,                   // [BC][S][D] bf16 (scaled); also output (attn)
    const u16* __restrict__ kfrag,  // [b][h][ch8][16 frags][512]
    const u16* __restrict__ vfrag,  // [b][h][ch8][16 frags][512] (scaled)
    u16* attnout,                   // == q buffer
    float* __restrict__ ent) {      // [B][H][S][Se] f32
  const int B = 2, H = 16, S = 4096, Se = 256, D = 1024;
  __shared__ u16 kvs[32 * 512];   // single buffer: frag 0..15=K,16..31=V : 32KB
  __shared__ u16 ldsP[4 * 4608];  // per wave: [c:4][s:32][pitch 36]
  const int tid = threadIdx.x;
  const int lane = tid & 63, wid = tid >> 6;
  const int lr = lane & 15, lg = lane >> 4;
  int bid = (int)blockIdx.x;
  bid = (bid & 7) * 128 + (bid >> 3);  // XCD swizzle (1024 blocks)
  const int sblk = bid & 31;
  const int h = (bid >> 5) & 15;
  const int b = bid >> 9;
  const int s0 = sblk * 128 + wid * 32;

  u16* Pw = ldsP + wid * 4608;

  // Q fragments: [c][st][ks], A-frag row=st*16+lr
  bf16x8 qf[4][2][2];
#pragma unroll
  for (int c = 0; c < 4; ++c)
#pragma unroll
    for (int st = 0; st < 2; ++st)
#pragma unroll
      for (int ks = 0; ks < 2; ++ks)
        qf[c][st][ks] =
            *(const bf16x8*)(q + ((c * B + b) * (long)S + s0 + st * 16 + lr) * D +
                             h * 64 + ks * 32 + lg * 8);

  const u16* kbh = kfrag + (long)(b * 16 + h) * 65536;
  const u16* vbh = vfrag + (long)(b * 16 + h) * 65536;
  float* entp = ent + ((long)(b * H + h) * S + s0 + lg * 4) * Se + lr;

  const float LN2 = 0.69314718056f;
  const int g0 = wid * 8;  // this wave stages fragments g0..g0+7

  f32x4 oacc[4][4][2] = {};  // [c][dsu][st]

#define STAGEKV(ch)                                                                    \
  do {                                                                                 \
    _Pragma("unroll") for (int j = 0; j < 8; ++j) {                                    \
      int f = g0 + j;                                                                  \
      const u16* src = (f < 16 ? kbh + (ch) * 8192 + f * 512                           \
                               : vbh + (ch) * 8192 + (f - 16) * 512) +                 \
                       lane * 8;                                                       \
      __builtin_amdgcn_global_load_lds(AS1P(src), AS3P(&kvs[f * 512]), 16, 0, 0);      \
    }                                                                                  \
  } while (0)

  // prologue: stage chunk 0 (syncthreads drains vmcnt before barrier)
  STAGEKV(0);
  __syncthreads();

#pragma unroll
  for (int ch = 0; ch < 8; ++ch) {
    // ---- QK^T: kf read once from shared LDS, used for both st subtiles
    f32x4 sacc[2][4][2] = {};  // [st][c][tsl]
#pragma unroll
    for (int c = 0; c < 4; ++c)
#pragma unroll
      for (int tsl = 0; tsl < 2; ++tsl)
#pragma unroll
        for (int ks = 0; ks < 2; ++ks) {
          bf16x8 kfv = *(const bf16x8*)(kvs + (c * 4 + tsl * 2 + ks) * 512 + lane * 8);
#pragma unroll
          for (int st = 0; st < 2; ++st)
            sacc[st][c][tsl] = MFMA16(qf[c][st][ks], kfv, sacc[st][c][tsl]);
        }

    // ---- in-lane component softmax + entropy + P write
#pragma unroll
    for (int st = 0; st < 2; ++st) {
#pragma unroll
      for (int tsl = 0; tsl < 2; ++tsl) {
#pragma unroll
        for (int r = 0; r < 4; ++r) {
          float t0 = sacc[st][0][tsl][r];
          float t1 = sacc[st][1][tsl][r];
          float t2 = sacc[st][2][tsl][r];
          float t3 = sacc[st][3][tsl][r];
          float e0 = __builtin_amdgcn_exp2f(t0);
          float e1 = __builtin_amdgcn_exp2f(t1);
          float e2 = __builtin_amdgcn_exp2f(t2);
          float e3 = __builtin_amdgcn_exp2f(t3);
          float sum = (e0 + e1) + (e2 + e3);
          float inv = __builtin_amdgcn_rcpf(sum);
          float l2s = __builtin_amdgcn_logf(sum);
          float w0 = e0 * inv, w1 = e1 * inv, w2 = e2 * inv, w3 = e3 * inv;
          float entv = (w0 * t0 + w1 * t1 + w2 * t2 + w3 * t3 - l2s) * LN2;
          __builtin_nontemporal_store(
              entv, entp + (st * 16 + r) * Se + ch * 32 + tsl * 16);
          int prow = st * 16 + lg * 4 + r;
          int pof = prow * 36 + tsl * 16 + lr;
          Pw[0 * 1152 + pof] = f2b(w0);
          Pw[1 * 1152 + pof] = f2b(w1);
          Pw[2 * 1152 + pof] = f2b(w2);
          Pw[3 * 1152 + pof] = f2b(w3);
        }
      }
    }

    // ---- PV: vf read once per (c,dsu), used for both st; pf per (c,st)
#pragma unroll
    for (int c = 0; c < 4; ++c) {
      bf16x8 pf[2];
#pragma unroll
      for (int st = 0; st < 2; ++st) {
        union { bf16x4 hh[2]; bf16x8 v; } pu;
        pu.hh[0] = *(const bf16x4*)(Pw + c * 1152 + (st * 16 + lr) * 36 + lg * 8);
        pu.hh[1] = *(const bf16x4*)(Pw + c * 1152 + (st * 16 + lr) * 36 + lg * 8 + 4);
        pf[st] = pu.v;
      }
#pragma unroll
      for (int dsu = 0; dsu < 4; ++dsu) {
        bf16x8 vfv = *(const bf16x8*)(kvs + (16 + c * 4 + dsu) * 512 + lane * 8);
        oacc[c][dsu][0] = MFMA16(pf[0], vfv, oacc[c][dsu][0]);
        oacc[c][dsu][1] = MFMA16(pf[1], vfv, oacc[c][dsu][1]);
      }
    }

    if (ch < 7) {
      __syncthreads();   // all waves done reading kvs for chunk ch
      STAGEKV(ch + 1);   // overwrite in place
      __syncthreads();   // drain (vmcnt0 inside) + visibility; other block's compute
                         // covers this stall (2 blocks/CU)
    }
  }

  // ---- epilogue: write attn out bf16 (into the q buffer region this block read)
#pragma unroll
  for (int c = 0; c < 4; ++c)
#pragma unroll
    for (int dsu = 0; dsu < 4; ++dsu)
#pragma unroll
      for (int st = 0; st < 2; ++st)
#pragma unroll
        for (int r = 0; r < 4; ++r) {
          long s = s0 + st * 16 + lg * 4 + r;
          attnout[((c * B + b) * (long)S + s) * D + h * 64 + dsu * 16 + lr] =
              f2b(oacc[c][dsu][st][r]);
        }
#undef STAGEKV
}

extern "C" void kernel_launch(void* const* d_in, const int* in_sizes, int n_in,
                              void* d_out, int out_size, void* d_ws, size_t ws_size,
                              hipStream_t stream) {
  const float* hs  = (const float*)d_in[0];  // [8,4096,1024]
  const float* ehs = (const float*)d_in[1];  // [8,256,2048]
  const float* Wq  = (const float*)d_in[2];  // [1024,1024]
  const float* Wk  = (const float*)d_in[3];  // [2048,1024]
  const float* Wv  = (const float*)d_in[4];  // [2048,1024]
  const float* Wo  = (const float*)d_in[5];  // [1024,1024]
  const float* bo  = (const float*)d_in[6];  // [1024]
  float* out = (float*)d_out;
  float* ent = out + (size_t)8 * 4096 * 1024;

  char* ws = (char*)d_ws;
  u16* hsb   = (u16*)(ws);              // 67,108,864 B bf16 hs (kept for residual)
  u16* ehsb  = (u16*)(ws + 67108864);   //  8,388,608 B (dead after KV GEMM)
  u16* kfrag = (u16*)(ws + 67108864);   //  4,194,304 B (overwrites ehsb after last use)
  u16* vfrag = (u16*)(ws + 71303168);   //  4,194,304 B
  u16* wqT   = (u16*)(ws + 75497472);   //  2,097,152 B
  u16* wkT   = (u16*)(ws + 77594624);   //  4,194,304 B  \ adjacent: acts as single
  u16* wvT   = (u16*)(ws + 81788928);   //  4,194,304 B  / Bt[2048][2048] for KV GEMM
  u16* woT   = (u16*)(ws + 85983232);   //  2,097,152 B
  u16* qb    = (u16*)(ws + 88080384);   // 67,108,864 B q; attn writes output in-place
  u16* kvb   = (u16*)(ws + 155189248);  //  8,388,608 B  [2048][2048]: k | v
  u16* vtb   = (u16*)(ws + 163577856);  //  4,194,304 B  (end: 167,772,160)

  const float QSCALE = 0.125f * 1.44269504f;  // attn.scale * log2(e)

  cvt_f32_bf16<<<2048, 256, 0, stream>>>(hs, hsb, (8 * 4096 * 1024) / 4);
  cvt_f32_bf16<<<512, 256, 0, stream>>>(ehs, ehsb, (8 * 256 * 2048) / 4);
  wtrans<<<1024, 256, 0, stream>>>(Wq, wqT, 1024, 1024);
  wtrans<<<2048, 256, 0, stream>>>(Wk, wkT, 2048, 1024);
  wtrans<<<2048, 256, 0, stream>>>(Wv, wvT, 2048, 1024);
  wtrans<<<1024, 256, 0, stream>>>(Wo, woT, 1024, 1024);
  // q = (hs @ Wq) * scale*log2e  -- 256^2 2-phase GEMM (proven)
  gemm256<0><<<(32768 / 256) * (1024 / 256), 512, 0, stream>>>(
      hsb, wqT, qb, nullptr, nullptr, nullptr, 32768, 1024, 1024, QSCALE);
  // [k|v] = ehs @ [Wk|Wv]  -- fused, 128^2 GEMM, 256 blocks (full GPU)
  gemm_bt<<<(2048 / 128) * (2048 / 128), 256, 0, stream>>>(
      ehsb, wkT, kvb, 2048, 2048, 2048, 1.0f);
  vtrans<<<2048, 256, 0, stream>>>(kvb, vtb);          // v-half, scaled by C/Se
  kfrag_build<<<1024, 256, 0, stream>>>(kvb, kfrag);   // k-half (ehsb now dead)
  vfrag_build<<<1024, 256, 0, stream>>>(vtb, vfrag);
  // fused component-softmax attention; output lands back in qb, entropy -> d_out
  attn_fused<<<1024, 256, 0, stream>>>(qb, kfrag, vfrag, qb, ent);
  // out = attn @ Wo + bo + hs(bf16 resid)  -- 256^2 2-phase GEMM
  gemm256<1><<<(32768 / 256) * (1024 / 256), 512, 0, stream>>>(
      qb, woT, nullptr, out, bo, hsb, 32768, 1024, 1024, 1.0f);
}

// Round 17
// 370.038 us; speedup vs baseline: 1.3783x; 1.0239x over previous
//
#include <hip/hip_runtime.h>

typedef unsigned short u16;
typedef __bf16 bf16x4 __attribute__((ext_vector_type(4)));
typedef __bf16 bf16x8 __attribute__((ext_vector_type(8)));
typedef float f32x4 __attribute__((ext_vector_type(4)));
typedef u16 u16x4 __attribute__((ext_vector_type(4)));
typedef u16 u16x8 __attribute__((ext_vector_type(8)));

#define AS1P(p) ((__attribute__((address_space(1))) void*)(unsigned long long)(p))
#define AS3P(p) ((__attribute__((address_space(3))) void*)(unsigned long long)(p))
#define MFMA16(a, b, c) __builtin_amdgcn_mfma_f32_16x16x32_bf16((a), (b), (c), 0, 0, 0)

__device__ __forceinline__ u16 f2b(float x) { return __builtin_bit_cast(u16, (__bf16)x); }
__device__ __forceinline__ float b2f(u16 u) {
  return __builtin_bit_cast(float, (unsigned)u << 16);
}

// ---------------- elementwise f32 -> bf16 ----------------
__global__ __launch_bounds__(256) void cvt_f32_bf16(const float* __restrict__ in,
                                                    u16* __restrict__ out, int n4) {
  int stride = gridDim.x * blockDim.x;
  for (int i = blockIdx.x * blockDim.x + threadIdx.x; i < n4; i += stride) {
    f32x4 v = *(const f32x4*)(in + (long)i * 4);
    u16x4 o;
    o[0] = f2b(v[0]); o[1] = f2b(v[1]); o[2] = f2b(v[2]); o[3] = f2b(v[3]);
    *(u16x4*)(out + (long)i * 4) = o;
  }
}

// ---------------- weight transpose f32[K][N] -> bf16[N][K] ----------------
__global__ __launch_bounds__(256) void wtrans(const float* __restrict__ W,
                                              u16* __restrict__ Wt, int K, int N) {
  __shared__ float tile[32][33];
  int nbk = K >> 5;
  int bk = blockIdx.x % nbk;
  int bn = blockIdx.x / nbk;
  int tx = threadIdx.x & 31, ty = threadIdx.x >> 5;  // 32 x 8
#pragma unroll
  for (int i = 0; i < 32; i += 8)
    tile[ty + i][tx] = W[(long)(bk * 32 + ty + i) * N + bn * 32 + tx];
  __syncthreads();
#pragma unroll
  for (int i = 0; i < 32; i += 8)
    Wt[(long)(bn * 32 + ty + i) * K + bk * 32 + tx] = f2b(tile[tx][ty + i]);
}

// ---------------- v transpose: kvb v-half [8][256][2048(+1024)] -> [8][1024][256] ------
__global__ __launch_bounds__(256) void vtrans(const u16* __restrict__ kvb,
                                              u16* __restrict__ vt) {
  __shared__ u16 tile[32][33];
  int bt = blockIdx.x & 7;          // Se/32
  int bd = (blockIdx.x >> 3) & 31;  // D/32
  int bc = blockIdx.x >> 8;         // 8
  int tx = threadIdx.x & 31, ty = threadIdx.x >> 5;
  const long ob = (long)bc * 1024 * 256;
  const float RS = 1.0f / 64.0f;  // C/Se
#pragma unroll
  for (int i = 0; i < 32; i += 8)
    tile[ty + i][tx] =
        kvb[((long)bc * 256 + bt * 32 + ty + i) * 2048 + 1024 + bd * 32 + tx];
  __syncthreads();
#pragma unroll
  for (int i = 0; i < 32; i += 8)
    vt[ob + (long)(bd * 32 + ty + i) * 256 + bt * 32 + tx] =
        f2b(b2f(tile[tx][ty + i]) * RS);
}

// ---------------- K fragmentizer: kvb k-half [BC][Se][2048] -> MFMA B-frag order -------
__global__ __launch_bounds__(256) void kfrag_build(const u16* __restrict__ kvb,
                                                   u16* __restrict__ kfrag) {
  int wv = ((int)blockIdx.x << 2) + (threadIdx.x >> 6);  // 0..4095
  int lane = threadIdx.x & 63, lr = lane & 15, lg = lane >> 4;
  int ks = wv & 1, tsl = (wv >> 1) & 1, c = (wv >> 2) & 3;
  int ch = (wv >> 4) & 7, h = (wv >> 7) & 15, b = (wv >> 11) & 1;
  const u16* src = kvb + ((long)(c * 2 + b) * 256 + ch * 32 + tsl * 16 + lr) * 2048 +
                   h * 64 + ks * 32 + lg * 8;
  *(bf16x8*)(kfrag + (long)wv * 512 + lane * 8) = *(const bf16x8*)src;
}

// ---------------- V fragmentizer: vtb[BC][D][Se] -> MFMA B-frag order ------------------
__global__ __launch_bounds__(256) void vfrag_build(const u16* __restrict__ vtb,
                                                   u16* __restrict__ vfrag) {
  int wv = ((int)blockIdx.x << 2) + (threadIdx.x >> 6);  // 0..4095
  int lane = threadIdx.x & 63, lr = lane & 15, lg = lane >> 4;
  int dsu = wv & 3, c = (wv >> 2) & 3;
  int ch = (wv >> 4) & 7, h = (wv >> 7) & 15, b = (wv >> 11) & 1;
  const u16* src = vtb + ((long)(c * 2 + b) * 1024 + h * 64 + dsu * 16 + lr) * 256 +
                   ch * 32 + lg * 8;
  *(bf16x8*)(vfrag + (long)wv * 512 + lane * 8) = *(const bf16x8*)src;
}

// ---------------- GEMM 128^2 (proven): C[M,N] = A[M,K] @ Bt[N,K]^T ---------------------
__global__ __launch_bounds__(256) void gemm_bt(
    const u16* __restrict__ A, const u16* __restrict__ Bt,
    u16* __restrict__ outb, int M, int N, int K, float ascale) {
  __shared__ u16 lA[128 * 64];
  __shared__ u16 lB[128 * 64];
  const int tid = threadIdx.x;
  const int lane = tid & 63;
  const int wid = tid >> 6;
  const int wm = wid >> 1, wn = wid & 1;
  const int lr = lane & 15, lg = lane >> 4;

  int bid = (int)blockIdx.x;
  int nwg = (int)gridDim.x;
  if ((nwg & 7) == 0) bid = (bid & 7) * (nwg >> 3) + (bid >> 3);

  const int nbn = N >> 7;
  const int bm = bid / nbn;
  const int bn = bid % nbn;
  const long arow0 = (long)bm * 128;
  const long brow0 = (long)bn * 128;

  f32x4 acc[4][4] = {};

  const int srow = tid >> 3;
  const int scol = tid & 7;

  for (int k0 = 0; k0 < K; k0 += 64) {
#pragma unroll
    for (int i = 0; i < 4; ++i) {
      int row = i * 32 + srow;
      int kc = scol ^ (row & 7);
      __builtin_amdgcn_global_load_lds(AS1P(A + (arow0 + row) * K + k0 + kc * 8),
                                       AS3P(lA + i * 2048 + (tid & ~63) * 8), 16, 0, 0);
    }
#pragma unroll
    for (int i = 0; i < 4; ++i) {
      int row = i * 32 + srow;
      int kc = scol ^ (row & 7);
      __builtin_amdgcn_global_load_lds(AS1P(Bt + (brow0 + row) * K + k0 + kc * 8),
                                       AS3P(lB + i * 2048 + (tid & ~63) * 8), 16, 0, 0);
    }
    asm volatile("s_waitcnt vmcnt(0)" ::: "memory");
    __syncthreads();

#pragma unroll
    for (int ks = 0; ks < 2; ++ks) {
      bf16x8 af[4], bfr[4];
#pragma unroll
      for (int m = 0; m < 4; ++m) {
        int row = wm * 64 + m * 16 + lr;
        int off = row * 128 + ks * 64 + lg * 16;
        off ^= (row & 7) << 4;
        af[m] = *(const bf16x8*)((const char*)lA + off);
      }
#pragma unroll
      for (int n = 0; n < 4; ++n) {
        int row = wn * 64 + n * 16 + lr;
        int off = row * 128 + ks * 64 + lg * 16;
        off ^= (row & 7) << 4;
        bfr[n] = *(const bf16x8*)((const char*)lB + off);
      }
#pragma unroll
      for (int m = 0; m < 4; ++m)
#pragma unroll
        for (int n = 0; n < 4; ++n)
          acc[m][n] = MFMA16(af[m], bfr[n], acc[m][n]);
    }
    __syncthreads();
  }

#pragma unroll
  for (int m = 0; m < 4; ++m)
#pragma unroll
    for (int n = 0; n < 4; ++n) {
      long col = brow0 + wn * 64 + n * 16 + lr;
#pragma unroll
      for (int r = 0; r < 4; ++r) {
        long row = arow0 + wm * 64 + m * 16 + lg * 4 + r;
        outb[row * N + col] = f2b(acc[m][n][r] * ascale);
      }
    }
}

// ---------------- GEMM 256^2 stage-ahead 2-phase (proven best) -------------------------
// MODE 0: write bf16 C*ascale.
// MODE 1: write f32 C + bias[n] + b2f(residb[m*N+n]) (nontemporal f32 out).
template <int MODE>
__global__ __launch_bounds__(512, 2) void gemm256(
    const u16* __restrict__ A, const u16* __restrict__ Bt,
    u16* __restrict__ outb, float* __restrict__ outf,
    const float* __restrict__ bias, const u16* __restrict__ residb,
    int M, int N, int K, float ascale) {
  __shared__ u16 lds[2][2][256 * 64];  // [buf][A=0/B=1][row*64 + slot*8 + e]
  const int tid = threadIdx.x;
  const int lane = tid & 63;
  const int wid = tid >> 6;      // 0..7
  const int wm = wid >> 2;       // 0..1
  const int wn = wid & 3;        // 0..3
  const int lr = lane & 15, lg = lane >> 4;

  int bid = (int)blockIdx.x;
  int nwg = (int)gridDim.x;
  bid = (bid & 7) * (nwg >> 3) + (bid >> 3);  // nwg % 8 == 0 for all our launches

  const int nbn = N >> 8;
  const int bm = bid / nbn;
  const int bn = bid % nbn;
  const long arow0 = (long)bm * 256;
  const long brow0 = (long)bn * 256;

  f32x4 acc[8][4] = {};

  const int srow = tid >> 3;  // 0..63
  const int scol = tid & 7;
  const int nt = K >> 6;

#define STAGE256(bf, t)                                                                \
  do {                                                                                 \
    int k0_ = (t) << 6;                                                                \
    _Pragma("unroll") for (int i = 0; i < 4; ++i) {                                    \
      int row = i * 64 + srow;                                                         \
      int kc = scol ^ (row & 7);                                                       \
      __builtin_amdgcn_global_load_lds(AS1P(A + (arow0 + row) * K + k0_ + kc * 8),     \
                                       AS3P(&lds[bf][0][0] + i * 4096 + (tid & ~63) * 8), \
                                       16, 0, 0);                                      \
    }                                                                                  \
    _Pragma("unroll") for (int i = 0; i < 4; ++i) {                                    \
      int row = i * 64 + srow;                                                         \
      int kc = scol ^ (row & 7);                                                       \
      __builtin_amdgcn_global_load_lds(AS1P(Bt + (brow0 + row) * K + k0_ + kc * 8),    \
                                       AS3P(&lds[bf][1][0] + i * 4096 + (tid & ~63) * 8), \
                                       16, 0, 0);                                      \
    }                                                                                  \
  } while (0)

#define COMPUTE256(bf)                                                                 \
  do {                                                                                 \
    _Pragma("unroll") for (int ks = 0; ks < 2; ++ks) {                                 \
      bf16x8 af[8], bfr[4];                                                            \
      _Pragma("unroll") for (int m = 0; m < 8; ++m) {                                  \
        int row = wm * 128 + m * 16 + lr;                                              \
        int off = row * 128 + ks * 64 + lg * 16;                                       \
        off ^= (row & 7) << 4;                                                         \
        af[m] = *(const bf16x8*)((const char*)&lds[bf][0][0] + off);                   \
      }                                                                                \
      _Pragma("unroll") for (int n = 0; n < 4; ++n) {                                  \
        int row = wn * 64 + n * 16 + lr;                                               \
        int off = row * 128 + ks * 64 + lg * 16;                                       \
        off ^= (row & 7) << 4;                                                         \
        bfr[n] = *(const bf16x8*)((const char*)&lds[bf][1][0] + off);                  \
      }                                                                                \
      _Pragma("unroll") for (int m = 0; m < 8; ++m)                                    \
          _Pragma("unroll") for (int n = 0; n < 4; ++n)                                \
              acc[m][n] = MFMA16(af[m], bfr[n], acc[m][n]);                            \
    }                                                                                  \
  } while (0)

  STAGE256(0, 0);
  asm volatile("s_waitcnt vmcnt(0)" ::: "memory");
  __syncthreads();
  int cur = 0;
  for (int t = 0; t < nt - 1; ++t) {
    STAGE256(cur ^ 1, t + 1);  // issue next-tile loads first: latency hides under compute
    COMPUTE256(cur);
    asm volatile("s_waitcnt vmcnt(0)" ::: "memory");
    __syncthreads();
    cur ^= 1;
  }
  COMPUTE256(cur);

  // epilogue: C/D layout row=(lane>>4)*4+r, col=lane&15
#pragma unroll
  for (int m = 0; m < 8; ++m)
#pragma unroll
    for (int n = 0; n < 4; ++n) {
      long col = brow0 + wn * 64 + n * 16 + lr;
#pragma unroll
      for (int r = 0; r < 4; ++r) {
        long row = arow0 + wm * 128 + m * 16 + lg * 4 + r;
        float v = acc[m][n][r];
        if (MODE == 1) {
          long idx = row * N + col;
          __builtin_nontemporal_store(v + bias[col] + b2f(residb[idx]), outf + idx);
        } else {
          outb[row * N + col] = f2b(v * ascale);
        }
      }
    }
#undef STAGE256
#undef COMPUTE256
}

// ---------------- fused decomposing attention (v8: best measured config, R12) ---------
// grid: 1024 blocks (b2 x h16 x sblk32), block 256 = 4 waves x 32 s-rows each.
// K/V fragments staged ONCE per block per chunk into LDS (32KB, via global_load_lds,
// naturally coalesced: fragments are contiguous 1KB), double-buffered, staged one full
// chunk ahead -> the single per-chunk __syncthreads() drain is covered by compute.
// 4 waves ds_read the shared copy; wave-private P slab (pitch 36, conflict-free).
// Output written in-place into the q buffer (disjoint regions, read-before-write).
__global__ __launch_bounds__(256, 1) void attn_fused(
    const u16* q,                   // [BC][S][D] bf16 (scaled); also output (attn)
    const u16* __restrict__ kfrag,  // [b][h][ch8][16 frags][512]
    const u16* __restrict__ vfrag,  // [b][h][ch8][16 frags][512] (scaled)
    u16* attnout,                   // == q buffer
    float* __restrict__ ent) {      // [B][H][S][Se] f32
  const int B = 2, H = 16, S = 4096, Se = 256, D = 1024;
  __shared__ u16 kvs[2][32 * 512];  // [buf][frag 0..15=K,16..31=V][lane*8] : 32KB/buf
  __shared__ u16 ldsP[4 * 4608];    // per wave: [c:4][s:32][pitch 36]
  const int tid = threadIdx.x;
  const int lane = tid & 63, wid = tid >> 6;
  const int lr = lane & 15, lg = lane >> 4;
  int bid = (int)blockIdx.x;
  bid = (bid & 7) * 128 + (bid >> 3);  // XCD swizzle (1024 blocks)
  const int sblk = bid & 31;
  const int h = (bid >> 5) & 15;
  const int b = bid >> 9;
  const int s0 = sblk * 128 + wid * 32;

  u16* Pw = ldsP + wid * 4608;

  // Q fragments: [c][st][ks], A-frag row=st*16+lr
  bf16x8 qf[4][2][2];
#pragma unroll
  for (int c = 0; c < 4; ++c)
#pragma unroll
    for (int st = 0; st < 2; ++st)
#pragma unroll
      for (int ks = 0; ks < 2; ++ks)
        qf[c][st][ks] =
            *(const bf16x8*)(q + ((c * B + b) * (long)S + s0 + st * 16 + lr) * D +
                             h * 64 + ks * 32 + lg * 8);

  const u16* kbh = kfrag + (long)(b * 16 + h) * 65536;
  const u16* vbh = vfrag + (long)(b * 16 + h) * 65536;
  float* entp = ent + ((long)(b * H + h) * S + s0 + lg * 4) * Se + lr;

  const float LN2 = 0.69314718056f;
  const int g0 = wid * 8;  // this wave stages fragments g0..g0+7

  f32x4 oacc[4][4][2] = {};  // [c][dsu][st]

#define STAGEKV(buf, ch)                                                               \
  do {                                                                                 \
    _Pragma("unroll") for (int j = 0; j < 8; ++j) {                                    \
      int f = g0 + j;                                                                  \
      const u16* src = (f < 16 ? kbh + (ch) * 8192 + f * 512                           \
                               : vbh + (ch) * 8192 + (f - 16) * 512) +                 \
                       lane * 8;                                                       \
      __builtin_amdgcn_global_load_lds(AS1P(src), AS3P(&kvs[buf][f * 512]), 16, 0, 0); \
    }                                                                                  \
  } while (0)

  // prologue: stage chunk 0
  STAGEKV(0, 0);
  __syncthreads();

#pragma unroll
  for (int ch = 0; ch < 8; ++ch) {
    const int cur = ch & 1;
    if (ch < 7) STAGEKV(cur ^ 1, ch + 1);  // stage-ahead: drained at chunk-end barrier
    const u16* KV = kvs[cur];

    // ---- QK^T: kf read once from shared LDS, used for both st subtiles
    f32x4 sacc[2][4][2] = {};  // [st][c][tsl]
#pragma unroll
    for (int c = 0; c < 4; ++c)
#pragma unroll
      for (int tsl = 0; tsl < 2; ++tsl)
#pragma unroll
        for (int ks = 0; ks < 2; ++ks) {
          bf16x8 kfv = *(const bf16x8*)(KV + (c * 4 + tsl * 2 + ks) * 512 + lane * 8);
#pragma unroll
          for (int st = 0; st < 2; ++st)
            sacc[st][c][tsl] = MFMA16(qf[c][st][ks], kfv, sacc[st][c][tsl]);
        }

    // ---- in-lane component softmax + entropy + P write
#pragma unroll
    for (int st = 0; st < 2; ++st) {
#pragma unroll
      for (int tsl = 0; tsl < 2; ++tsl) {
#pragma unroll
        for (int r = 0; r < 4; ++r) {
          float t0 = sacc[st][0][tsl][r];
          float t1 = sacc[st][1][tsl][r];
          float t2 = sacc[st][2][tsl][r];
          float t3 = sacc[st][3][tsl][r];
          float e0 = __builtin_amdgcn_exp2f(t0);
          float e1 = __builtin_amdgcn_exp2f(t1);
          float e2 = __builtin_amdgcn_exp2f(t2);
          float e3 = __builtin_amdgcn_exp2f(t3);
          float sum = (e0 + e1) + (e2 + e3);
          float inv = __builtin_amdgcn_rcpf(sum);
          float l2s = __builtin_amdgcn_logf(sum);
          float w0 = e0 * inv, w1 = e1 * inv, w2 = e2 * inv, w3 = e3 * inv;
          float entv = (w0 * t0 + w1 * t1 + w2 * t2 + w3 * t3 - l2s) * LN2;
          __builtin_nontemporal_store(
              entv, entp + (st * 16 + r) * Se + ch * 32 + tsl * 16);
          int prow = st * 16 + lg * 4 + r;
          int pof = prow * 36 + tsl * 16 + lr;
          Pw[0 * 1152 + pof] = f2b(w0);
          Pw[1 * 1152 + pof] = f2b(w1);
          Pw[2 * 1152 + pof] = f2b(w2);
          Pw[3 * 1152 + pof] = f2b(w3);
        }
      }
    }

    // ---- PV: vf read once per (c,dsu), used for both st; pf per (c,st)
#pragma unroll
    for (int c = 0; c < 4; ++c) {
      bf16x8 pf[2];
#pragma unroll
      for (int st = 0; st < 2; ++st) {
        union { bf16x4 hh[2]; bf16x8 v; } pu;
        pu.hh[0] = *(const bf16x4*)(Pw + c * 1152 + (st * 16 + lr) * 36 + lg * 8);
        pu.hh[1] = *(const bf16x4*)(Pw + c * 1152 + (st * 16 + lr) * 36 + lg * 8 + 4);
        pf[st] = pu.v;
      }
#pragma unroll
      for (int dsu = 0; dsu < 4; ++dsu) {
        bf16x8 vfv = *(const bf16x8*)(KV + (16 + c * 4 + dsu) * 512 + lane * 8);
        oacc[c][dsu][0] = MFMA16(pf[0], vfv, oacc[c][dsu][0]);
        oacc[c][dsu][1] = MFMA16(pf[1], vfv, oacc[c][dsu][1]);
      }
    }

    __syncthreads();  // drains stage(ch+1) loads + syncs waves before buffer swap
  }

  // ---- epilogue: write attn out bf16 (into the q buffer region this block read)
#pragma unroll
  for (int c = 0; c < 4; ++c)
#pragma unroll
    for (int dsu = 0; dsu < 4; ++dsu)
#pragma unroll
      for (int st = 0; st < 2; ++st)
#pragma unroll
        for (int r = 0; r < 4; ++r) {
          long s = s0 + st * 16 + lg * 4 + r;
          attnout[((c * B + b) * (long)S + s) * D + h * 64 + dsu * 16 + lr] =
              f2b(oacc[c][dsu][st][r]);
        }
#undef STAGEKV
}

extern "C" void kernel_launch(void* const* d_in, const int* in_sizes, int n_in,
                              void* d_out, int out_size, void* d_ws, size_t ws_size,
                              hipStream_t stream) {
  const float* hs  = (const float*)d_in[0];  // [8,4096,1024]
  const float* ehs = (const float*)d_in[1];  // [8,256,2048]
  const float* Wq  = (const float*)d_in[2];  // [1024,1024]
  const float* Wk  = (const float*)d_in[3];  // [2048,1024]
  const float* Wv  = (const float*)d_in[4];  // [2048,1024]
  const float* Wo  = (const float*)d_in[5];  // [1024,1024]
  const float* bo  = (const float*)d_in[6];  // [1024]
  float* out = (float*)d_out;
  float* ent = out + (size_t)8 * 4096 * 1024;

  char* ws = (char*)d_ws;
  u16* hsb   = (u16*)(ws);              // 67,108,864 B bf16 hs (kept for residual)
  u16* ehsb  = (u16*)(ws + 67108864);   //  8,388,608 B (dead after KV GEMM)
  u16* kfrag = (u16*)(ws + 67108864);   //  4,194,304 B (overwrites ehsb after last use)
  u16* vfrag = (u16*)(ws + 71303168);   //  4,194,304 B
  u16* wqT   = (u16*)(ws + 75497472);   //  2,097,152 B
  u16* wkT   = (u16*)(ws + 77594624);   //  4,194,304 B  \ adjacent: acts as single
  u16* wvT   = (u16*)(ws + 81788928);   //  4,194,304 B  / Bt[2048][2048] for KV GEMM
  u16* woT   = (u16*)(ws + 85983232);   //  2,097,152 B
  u16* qb    = (u16*)(ws + 88080384);   // 67,108,864 B q; attn writes output in-place
  u16* kvb   = (u16*)(ws + 155189248);  //  8,388,608 B  [2048][2048]: k | v
  u16* vtb   = (u16*)(ws + 163577856);  //  4,194,304 B  (end: 167,772,160)

  const float QSCALE = 0.125f * 1.44269504f;  // attn.scale * log2(e)

  cvt_f32_bf16<<<2048, 256, 0, stream>>>(hs, hsb, (8 * 4096 * 1024) / 4);
  cvt_f32_bf16<<<512, 256, 0, stream>>>(ehs, ehsb, (8 * 256 * 2048) / 4);
  wtrans<<<1024, 256, 0, stream>>>(Wq, wqT, 1024, 1024);
  wtrans<<<2048, 256, 0, stream>>>(Wk, wkT, 2048, 1024);
  wtrans<<<2048, 256, 0, stream>>>(Wv, wvT, 2048, 1024);
  wtrans<<<1024, 256, 0, stream>>>(Wo, woT, 1024, 1024);
  // q = (hs @ Wq) * scale*log2e  -- 256^2 2-phase GEMM (proven)
  gemm256<0><<<(32768 / 256) * (1024 / 256), 512, 0, stream>>>(
      hsb, wqT, qb, nullptr, nullptr, nullptr, 32768, 1024, 1024, QSCALE);
  // [k|v] = ehs @ [Wk|Wv]  -- fused, 128^2 GEMM, 256 blocks (full GPU)
  gemm_bt<<<(2048 / 128) * (2048 / 128), 256, 0, stream>>>(
      ehsb, wkT, kvb, 2048, 2048, 2048, 1.0f);
  vtrans<<<2048, 256, 0, stream>>>(kvb, vtb);          // v-half, scaled by C/Se
  kfrag_build<<<1024, 256, 0, stream>>>(kvb, kfrag);   // k-half (ehsb now dead)
  vfrag_build<<<1024, 256, 0, stream>>>(vtb, vfrag);
  // fused component-softmax attention; output lands back in qb, entropy -> d_out
  attn_fused<<<1024, 256, 0, stream>>>(qb, kfrag, vfrag, qb, ent);
  // out = attn @ Wo + bo + hs(bf16 resid)  -- 256^2 2-phase GEMM
  gemm256<1><<<(32768 / 256) * (1024 / 256), 512, 0, stream>>>(
      qb, woT, nullptr, out, bo, hsb, 32768, 1024, 1024, 1.0f);
}

// Round 18
// 364.935 us; speedup vs baseline: 1.3976x; 1.0140x over previous
//
#include <hip/hip_runtime.h>

typedef unsigned short u16;
typedef __bf16 bf16x4 __attribute__((ext_vector_type(4)));
typedef __bf16 bf16x8 __attribute__((ext_vector_type(8)));
typedef float f32x4 __attribute__((ext_vector_type(4)));
typedef u16 u16x4 __attribute__((ext_vector_type(4)));
typedef u16 u16x8 __attribute__((ext_vector_type(8)));

#define AS1P(p) ((__attribute__((address_space(1))) void*)(unsigned long long)(p))
#define AS3P(p) ((__attribute__((address_space(3))) void*)(unsigned long long)(p))
#define MFMA16(a, b, c) __builtin_amdgcn_mfma_f32_16x16x32_bf16((a), (b), (c), 0, 0, 0)

__device__ __forceinline__ u16 f2b(float x) { return __builtin_bit_cast(u16, (__bf16)x); }
__device__ __forceinline__ float b2f(u16 u) {
  return __builtin_bit_cast(float, (unsigned)u << 16);
}

// ---------------- elementwise f32 -> bf16 (hs only; big stream) ----------------
__global__ __launch_bounds__(256) void cvt_f32_bf16(const float* __restrict__ in,
                                                    u16* __restrict__ out, int n4) {
  int stride = gridDim.x * blockDim.x;
  for (int i = blockIdx.x * blockDim.x + threadIdx.x; i < n4; i += stride) {
    f32x4 v = *(const f32x4*)(in + (long)i * 4);
    u16x4 o;
    o[0] = f2b(v[0]); o[1] = f2b(v[1]); o[2] = f2b(v[2]); o[3] = f2b(v[3]);
    *(u16x4*)(out + (long)i * 4) = o;
  }
}

// ---------------- fused prep: ehs convert + all 4 weight transposes -------------------
// One launch replaces 5 small kernels (saves launch/tail overhead).
// Block ranges: [0,512) ehs cvt; [512,1536) Wq; [1536,3584) Wk; [3584,5632) Wv;
// [5632,6656) Wo.  wtrans body: f32 [K][N] -> bf16 [N][K] via 32x32 LDS tile.
__device__ __forceinline__ void wtrans_body(const float* __restrict__ W,
                                            u16* __restrict__ Wt, int K, int N,
                                            int blk, int tid) {
  __shared__ float tile[32][33];
  int nbk = K >> 5;
  int bk = blk % nbk;
  int bn = blk / nbk;
  int tx = tid & 31, ty = tid >> 5;  // 32 x 8
#pragma unroll
  for (int i = 0; i < 32; i += 8)
    tile[ty + i][tx] = W[(long)(bk * 32 + ty + i) * N + bn * 32 + tx];
  __syncthreads();
#pragma unroll
  for (int i = 0; i < 32; i += 8)
    Wt[(long)(bn * 32 + ty + i) * K + bk * 32 + tx] = f2b(tile[tx][ty + i]);
}

__global__ __launch_bounds__(256) void prep(
    const float* __restrict__ ehs, u16* __restrict__ ehsb,
    const float* __restrict__ Wq, u16* __restrict__ wqT,
    const float* __restrict__ Wk, u16* __restrict__ wkT,
    const float* __restrict__ Wv, u16* __restrict__ wvT,
    const float* __restrict__ Wo, u16* __restrict__ woT) {
  int blk = (int)blockIdx.x;
  int tid = threadIdx.x;
  if (blk < 512) {
    // ehs f32->bf16: 512 blocks x 256 thr x 8 elems = 1,048,576 x 8? (4M elems /4 = 1M x4)
    int i = blk * 256 + tid;  // 131072 i-steps of 8 f32... use 2x f32x4 per thread
    const int n4 = (8 * 256 * 2048) / 4;  // 1,048,576 vec4
    for (; i < n4; i += 512 * 256) {
      f32x4 v = *(const f32x4*)(ehs + (long)i * 4);
      u16x4 o;
      o[0] = f2b(v[0]); o[1] = f2b(v[1]); o[2] = f2b(v[2]); o[3] = f2b(v[3]);
      *(u16x4*)(ehsb + (long)i * 4) = o;
    }
  } else if (blk < 1536) {
    wtrans_body(Wq, wqT, 1024, 1024, blk - 512, tid);
  } else if (blk < 3584) {
    wtrans_body(Wk, wkT, 2048, 1024, blk - 1536, tid);
  } else if (blk < 5632) {
    wtrans_body(Wv, wvT, 2048, 1024, blk - 3584, tid);
  } else {
    wtrans_body(Wo, woT, 1024, 1024, blk - 5632, tid);
  }
}

// ---------------- v transpose: kvb v-half [8][256][2048(+1024)] -> [8][1024][256] ------
__global__ __launch_bounds__(256) void vtrans(const u16* __restrict__ kvb,
                                              u16* __restrict__ vt) {
  __shared__ u16 tile[32][33];
  int bt = blockIdx.x & 7;          // Se/32
  int bd = (blockIdx.x >> 3) & 31;  // D/32
  int bc = blockIdx.x >> 8;         // 8
  int tx = threadIdx.x & 31, ty = threadIdx.x >> 5;
  const long ob = (long)bc * 1024 * 256;
  const float RS = 1.0f / 64.0f;  // C/Se
#pragma unroll
  for (int i = 0; i < 32; i += 8)
    tile[ty + i][tx] =
        kvb[((long)bc * 256 + bt * 32 + ty + i) * 2048 + 1024 + bd * 32 + tx];
  __syncthreads();
#pragma unroll
  for (int i = 0; i < 32; i += 8)
    vt[ob + (long)(bd * 32 + ty + i) * 256 + bt * 32 + tx] =
        f2b(b2f(tile[tx][ty + i]) * RS);
}

// ---------------- K fragmentizer: kvb k-half [BC][Se][2048] -> MFMA B-frag order -------
__global__ __launch_bounds__(256) void kfrag_build(const u16* __restrict__ kvb,
                                                   u16* __restrict__ kfrag) {
  int wv = ((int)blockIdx.x << 2) + (threadIdx.x >> 6);  // 0..4095
  int lane = threadIdx.x & 63, lr = lane & 15, lg = lane >> 4;
  int ks = wv & 1, tsl = (wv >> 1) & 1, c = (wv >> 2) & 3;
  int ch = (wv >> 4) & 7, h = (wv >> 7) & 15, b = (wv >> 11) & 1;
  const u16* src = kvb + ((long)(c * 2 + b) * 256 + ch * 32 + tsl * 16 + lr) * 2048 +
                   h * 64 + ks * 32 + lg * 8;
  *(bf16x8*)(kfrag + (long)wv * 512 + lane * 8) = *(const bf16x8*)src;
}

// ---------------- V fragmentizer: vtb[BC][D][Se] -> MFMA B-frag order ------------------
__global__ __launch_bounds__(256) void vfrag_build(const u16* __restrict__ vtb,
                                                   u16* __restrict__ vfrag) {
  int wv = ((int)blockIdx.x << 2) + (threadIdx.x >> 6);  // 0..4095
  int lane = threadIdx.x & 63, lr = lane & 15, lg = lane >> 4;
  int dsu = wv & 3, c = (wv >> 2) & 3;
  int ch = (wv >> 4) & 7, h = (wv >> 7) & 15, b = (wv >> 11) & 1;
  const u16* src = vtb + ((long)(c * 2 + b) * 1024 + h * 64 + dsu * 16 + lr) * 256 +
                   ch * 32 + lg * 8;
  *(bf16x8*)(vfrag + (long)wv * 512 + lane * 8) = *(const bf16x8*)src;
}

// ---------------- GEMM 128^2 (proven): C[M,N] = A[M,K] @ Bt[N,K]^T ---------------------
__global__ __launch_bounds__(256) void gemm_bt(
    const u16* __restrict__ A, const u16* __restrict__ Bt,
    u16* __restrict__ outb, int M, int N, int K, float ascale) {
  __shared__ u16 lA[128 * 64];
  __shared__ u16 lB[128 * 64];
  const int tid = threadIdx.x;
  const int lane = tid & 63;
  const int wid = tid >> 6;
  const int wm = wid >> 1, wn = wid & 1;
  const int lr = lane & 15, lg = lane >> 4;

  int bid = (int)blockIdx.x;
  int nwg = (int)gridDim.x;
  if ((nwg & 7) == 0) bid = (bid & 7) * (nwg >> 3) + (bid >> 3);

  const int nbn = N >> 7;
  const int bm = bid / nbn;
  const int bn = bid % nbn;
  const long arow0 = (long)bm * 128;
  const long brow0 = (long)bn * 128;

  f32x4 acc[4][4] = {};

  const int srow = tid >> 3;
  const int scol = tid & 7;

  for (int k0 = 0; k0 < K; k0 += 64) {
#pragma unroll
    for (int i = 0; i < 4; ++i) {
      int row = i * 32 + srow;
      int kc = scol ^ (row & 7);
      __builtin_amdgcn_global_load_lds(AS1P(A + (arow0 + row) * K + k0 + kc * 8),
                                       AS3P(lA + i * 2048 + (tid & ~63) * 8), 16, 0, 0);
    }
#pragma unroll
    for (int i = 0; i < 4; ++i) {
      int row = i * 32 + srow;
      int kc = scol ^ (row & 7);
      __builtin_amdgcn_global_load_lds(AS1P(Bt + (brow0 + row) * K + k0 + kc * 8),
                                       AS3P(lB + i * 2048 + (tid & ~63) * 8), 16, 0, 0);
    }
    asm volatile("s_waitcnt vmcnt(0)" ::: "memory");
    __syncthreads();

#pragma unroll
    for (int ks = 0; ks < 2; ++ks) {
      bf16x8 af[4], bfr[4];
#pragma unroll
      for (int m = 0; m < 4; ++m) {
        int row = wm * 64 + m * 16 + lr;
        int off = row * 128 + ks * 64 + lg * 16;
        off ^= (row & 7) << 4;
        af[m] = *(const bf16x8*)((const char*)lA + off);
      }
#pragma unroll
      for (int n = 0; n < 4; ++n) {
        int row = wn * 64 + n * 16 + lr;
        int off = row * 128 + ks * 64 + lg * 16;
        off ^= (row & 7) << 4;
        bfr[n] = *(const bf16x8*)((const char*)lB + off);
      }
#pragma unroll
      for (int m = 0; m < 4; ++m)
#pragma unroll
        for (int n = 0; n < 4; ++n)
          acc[m][n] = MFMA16(af[m], bfr[n], acc[m][n]);
    }
    __syncthreads();
  }

#pragma unroll
  for (int m = 0; m < 4; ++m)
#pragma unroll
    for (int n = 0; n < 4; ++n) {
      long col = brow0 + wn * 64 + n * 16 + lr;
#pragma unroll
      for (int r = 0; r < 4; ++r) {
        long row = arow0 + wm * 64 + m * 16 + lg * 4 + r;
        outb[row * N + col] = f2b(acc[m][n][r] * ascale);
      }
    }
}

// ---------------- GEMM 256^2 stage-ahead 2-phase (proven best) -------------------------
// MODE 0: write bf16 C*ascale.
// MODE 1: write f32 C + bias[n] + b2f(residb[m*N+n]) (nontemporal f32 out).
template <int MODE>
__global__ __launch_bounds__(512, 2) void gemm256(
    const u16* __restrict__ A, const u16* __restrict__ Bt,
    u16* __restrict__ outb, float* __restrict__ outf,
    const float* __restrict__ bias, const u16* __restrict__ residb,
    int M, int N, int K, float ascale) {
  __shared__ u16 lds[2][2][256 * 64];  // [buf][A=0/B=1][row*64 + slot*8 + e]
  const int tid = threadIdx.x;
  const int lane = tid & 63;
  const int wid = tid >> 6;      // 0..7
  const int wm = wid >> 2;       // 0..1
  const int wn = wid & 3;        // 0..3
  const int lr = lane & 15, lg = lane >> 4;

  int bid = (int)blockIdx.x;
  int nwg = (int)gridDim.x;
  bid = (bid & 7) * (nwg >> 3) + (bid >> 3);  // nwg % 8 == 0 for all our launches

  const int nbn = N >> 8;
  const int bm = bid / nbn;
  const int bn = bid % nbn;
  const long arow0 = (long)bm * 256;
  const long brow0 = (long)bn * 256;

  f32x4 acc[8][4] = {};

  const int srow = tid >> 3;  // 0..63
  const int scol = tid & 7;
  const int nt = K >> 6;

#define STAGE256(bf, t)                                                                \
  do {                                                                                 \
    int k0_ = (t) << 6;                                                                \
    _Pragma("unroll") for (int i = 0; i < 4; ++i) {                                    \
      int row = i * 64 + srow;                                                         \
      int kc = scol ^ (row & 7);                                                       \
      __builtin_amdgcn_global_load_lds(AS1P(A + (arow0 + row) * K + k0_ + kc * 8),     \
                                       AS3P(&lds[bf][0][0] + i * 4096 + (tid & ~63) * 8), \
                                       16, 0, 0);                                      \
    }                                                                                  \
    _Pragma("unroll") for (int i = 0; i < 4; ++i) {                                    \
      int row = i * 64 + srow;                                                         \
      int kc = scol ^ (row & 7);                                                       \
      __builtin_amdgcn_global_load_lds(AS1P(Bt + (brow0 + row) * K + k0_ + kc * 8),    \
                                       AS3P(&lds[bf][1][0] + i * 4096 + (tid & ~63) * 8), \
                                       16, 0, 0);                                      \
    }                                                                                  \
  } while (0)

#define COMPUTE256(bf)                                                                 \
  do {                                                                                 \
    _Pragma("unroll") for (int ks = 0; ks < 2; ++ks) {                                 \
      bf16x8 af[8], bfr[4];                                                            \
      _Pragma("unroll") for (int m = 0; m < 8; ++m) {                                  \
        int row = wm * 128 + m * 16 + lr;                                              \
        int off = row * 128 + ks * 64 + lg * 16;                                       \
        off ^= (row & 7) << 4;                                                         \
        af[m] = *(const bf16x8*)((const char*)&lds[bf][0][0] + off);                   \
      }                                                                                \
      _Pragma("unroll") for (int n = 0; n < 4; ++n) {                                  \
        int row = wn * 64 + n * 16 + lr;                                               \
        int off = row * 128 + ks * 64 + lg * 16;                                       \
        off ^= (row & 7) << 4;                                                         \
        bfr[n] = *(const bf16x8*)((const char*)&lds[bf][1][0] + off);                  \
      }                                                                                \
      _Pragma("unroll") for (int m = 0; m < 8; ++m)                                    \
          _Pragma("unroll") for (int n = 0; n < 4; ++n)                                \
              acc[m][n] = MFMA16(af[m], bfr[n], acc[m][n]);                            \
    }                                                                                  \
  } while (0)

  STAGE256(0, 0);
  asm volatile("s_waitcnt vmcnt(0)" ::: "memory");
  __syncthreads();
  int cur = 0;
  for (int t = 0; t < nt - 1; ++t) {
    STAGE256(cur ^ 1, t + 1);  // issue next-tile loads first: latency hides under compute
    COMPUTE256(cur);
    asm volatile("s_waitcnt vmcnt(0)" ::: "memory");
    __syncthreads();
    cur ^= 1;
  }
  COMPUTE256(cur);

  // epilogue: C/D layout row=(lane>>4)*4+r, col=lane&15
#pragma unroll
  for (int m = 0; m < 8; ++m)
#pragma unroll
    for (int n = 0; n < 4; ++n) {
      long col = brow0 + wn * 64 + n * 16 + lr;
#pragma unroll
      for (int r = 0; r < 4; ++r) {
        long row = arow0 + wm * 128 + m * 16 + lg * 4 + r;
        float v = acc[m][n][r];
        if (MODE == 1) {
          long idx = row * N + col;
          __builtin_nontemporal_store(v + bias[col] + b2f(residb[idx]), outf + idx);
        } else {
          outb[row * N + col] = f2b(v * ascale);
        }
      }
    }
#undef STAGE256
#undef COMPUTE256
}

// ---------------- fused decomposing attention (v8: best measured config) --------------
__global__ __launch_bounds__(256, 1) void attn_fused(
    const u16* q,                   // [BC][S][D] bf16 (scaled); also output (attn)
    const u16* __restrict__ kfrag,  // [b][h][ch8][16 frags][512]
    const u16* __restrict__ vfrag,  // [b][h][ch8][16 frags][512] (scaled)
    u16* attnout,                   // == q buffer
    float* __restrict__ ent) {      // [B][H][S][Se] f32
  const int B = 2, H = 16, S = 4096, Se = 256, D = 1024;
  __shared__ u16 kvs[2][32 * 512];  // [buf][frag 0..15=K,16..31=V][lane*8] : 32KB/buf
  __shared__ u16 ldsP[4 * 4608];    // per wave: [c:4][s:32][pitch 36]
  const int tid = threadIdx.x;
  const int lane = tid & 63, wid = tid >> 6;
  const int lr = lane & 15, lg = lane >> 4;
  int bid = (int)blockIdx.x;
  bid = (bid & 7) * 128 + (bid >> 3);  // XCD swizzle (1024 blocks)
  const int sblk = bid & 31;
  const int h = (bid >> 5) & 15;
  const int b = bid >> 9;
  const int s0 = sblk * 128 + wid * 32;

  u16* Pw = ldsP + wid * 4608;

  // Q fragments: [c][st][ks], A-frag row=st*16+lr
  bf16x8 qf[4][2][2];
#pragma unroll
  for (int c = 0; c < 4; ++c)
#pragma unroll
    for (int st = 0; st < 2; ++st)
#pragma unroll
      for (int ks = 0; ks < 2; ++ks)
        qf[c][st][ks] =
            *(const bf16x8*)(q + ((c * B + b) * (long)S + s0 + st * 16 + lr) * D +
                             h * 64 + ks * 32 + lg * 8);

  const u16* kbh = kfrag + (long)(b * 16 + h) * 65536;
  const u16* vbh = vfrag + (long)(b * 16 + h) * 65536;
  float* entp = ent + ((long)(b * H + h) * S + s0 + lg * 4) * Se + lr;

  const float LN2 = 0.69314718056f;
  const int g0 = wid * 8;  // this wave stages fragments g0..g0+7

  f32x4 oacc[4][4][2] = {};  // [c][dsu][st]

#define STAGEKV(buf, ch)                                                               \
  do {                                                                                 \
    _Pragma("unroll") for (int j = 0; j < 8; ++j) {                                    \
      int f = g0 + j;                                                                  \
      const u16* src = (f < 16 ? kbh + (ch) * 8192 + f * 512                           \
                               : vbh + (ch) * 8192 + (f - 16) * 512) +                 \
                       lane * 8;                                                       \
      __builtin_amdgcn_global_load_lds(AS1P(src), AS3P(&kvs[buf][f * 512]), 16, 0, 0); \
    }                                                                                  \
  } while (0)

  // prologue: stage chunk 0
  STAGEKV(0, 0);
  __syncthreads();

#pragma unroll
  for (int ch = 0; ch < 8; ++ch) {
    const int cur = ch & 1;
    if (ch < 7) STAGEKV(cur ^ 1, ch + 1);  // stage-ahead: drained at chunk-end barrier
    const u16* KV = kvs[cur];

    // ---- QK^T: kf read once from shared LDS, used for both st subtiles
    f32x4 sacc[2][4][2] = {};  // [st][c][tsl]
#pragma unroll
    for (int c = 0; c < 4; ++c)
#pragma unroll
      for (int tsl = 0; tsl < 2; ++tsl)
#pragma unroll
        for (int ks = 0; ks < 2; ++ks) {
          bf16x8 kfv = *(const bf16x8*)(KV + (c * 4 + tsl * 2 + ks) * 512 + lane * 8);
#pragma unroll
          for (int st = 0; st < 2; ++st)
            sacc[st][c][tsl] = MFMA16(qf[c][st][ks], kfv, sacc[st][c][tsl]);
        }

    // ---- in-lane component softmax + entropy + P write
#pragma unroll
    for (int st = 0; st < 2; ++st) {
#pragma unroll
      for (int tsl = 0; tsl < 2; ++tsl) {
#pragma unroll
        for (int r = 0; r < 4; ++r) {
          float t0 = sacc[st][0][tsl][r];
          float t1 = sacc[st][1][tsl][r];
          float t2 = sacc[st][2][tsl][r];
          float t3 = sacc[st][3][tsl][r];
          float e0 = __builtin_amdgcn_exp2f(t0);
          float e1 = __builtin_amdgcn_exp2f(t1);
          float e2 = __builtin_amdgcn_exp2f(t2);
          float e3 = __builtin_amdgcn_exp2f(t3);
          float sum = (e0 + e1) + (e2 + e3);
          float inv = __builtin_amdgcn_rcpf(sum);
          float l2s = __builtin_amdgcn_logf(sum);
          float w0 = e0 * inv, w1 = e1 * inv, w2 = e2 * inv, w3 = e3 * inv;
          float entv = (w0 * t0 + w1 * t1 + w2 * t2 + w3 * t3 - l2s) * LN2;
          __builtin_nontemporal_store(
              entv, entp + (st * 16 + r) * Se + ch * 32 + tsl * 16);
          int prow = st * 16 + lg * 4 + r;
          int pof = prow * 36 + tsl * 16 + lr;
          Pw[0 * 1152 + pof] = f2b(w0);
          Pw[1 * 1152 + pof] = f2b(w1);
          Pw[2 * 1152 + pof] = f2b(w2);
          Pw[3 * 1152 + pof] = f2b(w3);
        }
      }
    }

    // ---- PV: vf read once per (c,dsu), used for both st; pf per (c,st)
#pragma unroll
    for (int c = 0; c < 4; ++c) {
      bf16x8 pf[2];
#pragma unroll
      for (int st = 0; st < 2; ++st) {
        union { bf16x4 hh[2]; bf16x8 v; } pu;
        pu.hh[0] = *(const bf16x4*)(Pw + c * 1152 + (st * 16 + lr) * 36 + lg * 8);
        pu.hh[1] = *(const bf16x4*)(Pw + c * 1152 + (st * 16 + lr) * 36 + lg * 8 + 4);
        pf[st] = pu.v;
      }
#pragma unroll
      for (int dsu = 0; dsu < 4; ++dsu) {
        bf16x8 vfv = *(const bf16x8*)(KV + (16 + c * 4 + dsu) * 512 + lane * 8);
        oacc[c][dsu][0] = MFMA16(pf[0], vfv, oacc[c][dsu][0]);
        oacc[c][dsu][1] = MFMA16(pf[1], vfv, oacc[c][dsu][1]);
      }
    }

    __syncthreads();  // drains stage(ch+1) loads + syncs waves before buffer swap
  }

  // ---- epilogue: write attn out bf16 (into the q buffer region this block read)
#pragma unroll
  for (int c = 0; c < 4; ++c)
#pragma unroll
    for (int dsu = 0; dsu < 4; ++dsu)
#pragma unroll
      for (int st = 0; st < 2; ++st)
#pragma unroll
        for (int r = 0; r < 4; ++r) {
          long s = s0 + st * 16 + lg * 4 + r;
          attnout[((c * B + b) * (long)S + s) * D + h * 64 + dsu * 16 + lr] =
              f2b(oacc[c][dsu][st][r]);
        }
#undef STAGEKV
}

extern "C" void kernel_launch(void* const* d_in, const int* in_sizes, int n_in,
                              void* d_out, int out_size, void* d_ws, size_t ws_size,
                              hipStream_t stream) {
  const float* hs  = (const float*)d_in[0];  // [8,4096,1024]
  const float* ehs = (const float*)d_in[1];  // [8,256,2048]
  const float* Wq  = (const float*)d_in[2];  // [1024,1024]
  const float* Wk  = (const float*)d_in[3];  // [2048,1024]
  const float* Wv  = (const float*)d_in[4];  // [2048,1024]
  const float* Wo  = (const float*)d_in[5];  // [1024,1024]
  const float* bo  = (const float*)d_in[6];  // [1024]
  float* out = (float*)d_out;
  float* ent = out + (size_t)8 * 4096 * 1024;

  char* ws = (char*)d_ws;
  u16* hsb   = (u16*)(ws);              // 67,108,864 B bf16 hs (kept for residual)
  u16* ehsb  = (u16*)(ws + 67108864);   //  8,388,608 B (dead after KV GEMM)
  u16* kfrag = (u16*)(ws + 67108864);   //  4,194,304 B (overwrites ehsb after last use)
  u16* vfrag = (u16*)(ws + 71303168);   //  4,194,304 B
  u16* wqT   = (u16*)(ws + 75497472);   //  2,097,152 B
  u16* wkT   = (u16*)(ws + 77594624);   //  4,194,304 B  \ adjacent: acts as single
  u16* wvT   = (u16*)(ws + 81788928);   //  4,194,304 B  / Bt[2048][2048] for KV GEMM
  u16* woT   = (u16*)(ws + 85983232);   //  2,097,152 B
  u16* qb    = (u16*)(ws + 88080384);   // 67,108,864 B q; attn writes output in-place
  u16* kvb   = (u16*)(ws + 155189248);  //  8,388,608 B  [2048][2048]: k | v
  u16* vtb   = (u16*)(ws + 163577856);  //  4,194,304 B  (end: 167,772,160)

  const float QSCALE = 0.125f * 1.44269504f;  // attn.scale * log2(e)

  cvt_f32_bf16<<<2048, 256, 0, stream>>>(hs, hsb, (8 * 4096 * 1024) / 4);
  // fused prep: ehs convert + 4 weight transposes in ONE launch (was 5 launches)
  prep<<<6656, 256, 0, stream>>>(ehs, ehsb, Wq, wqT, Wk, wkT, Wv, wvT, Wo, woT);
  // q = (hs @ Wq) * scale*log2e  -- 256^2 2-phase GEMM (proven)
  gemm256<0><<<(32768 / 256) * (1024 / 256), 512, 0, stream>>>(
      hsb, wqT, qb, nullptr, nullptr, nullptr, 32768, 1024, 1024, QSCALE);
  // [k|v] = ehs @ [Wk|Wv]  -- fused, 128^2 GEMM, 256 blocks (full GPU)
  gemm_bt<<<(2048 / 128) * (2048 / 128), 256, 0, stream>>>(
      ehsb, wkT, kvb, 2048, 2048, 2048, 1.0f);
  vtrans<<<2048, 256, 0, stream>>>(kvb, vtb);          // v-half, scaled by C/Se
  kfrag_build<<<1024, 256, 0, stream>>>(kvb, kfrag);   // k-half (ehsb now dead)
  vfrag_build<<<1024, 256, 0, stream>>>(vtb, vfrag);
  // fused component-softmax attention; output lands back in qb, entropy -> d_out
  attn_fused<<<1024, 256, 0, stream>>>(qb, kfrag, vfrag, qb, ent);
  // out = attn @ Wo + bo + hs(bf16 resid)  -- 256^2 2-phase GEMM
  gemm256<1><<<(32768 / 256) * (1024 / 256), 512, 0, stream>>>(
      qb, woT, nullptr, out, bo, hsb, 32768, 1024, 1024, 1.0f);
}